// Round 1
// baseline (4564.352 us; speedup 1.0000x reference)
//
#include <hip/hip_runtime.h>
#include <math.h>

#define NPTS 8192
#define KNN 40
#define DD 32
#define CIN 16
#define NTILE 2048

// ---- ws layout (float offsets) ----
#define OFF_H      0u         // 8192*32
#define OFF_XIN    262144u    // 8192*32
#define OFF_HL     524288u    // 8192*32
#define OFF_SL     786432u    // 8192*4 (float4)
#define OFF_ESQ    819200u    // 8192*40
#define OFF_O      1146880u   // 8192*32
#define OFF_IDX    1409024u   // 8192*40 (int)
#define OFF_SUMD   1736704u   // 8192
#define OFF_INDEG  1744896u   // 8192
#define OFF_STATS  1753088u   // 136: bn1 s[32] ss[32], bn2 s[32] ss[32], loss1, loss2
#define OFF_AB     1753224u   // 128: a1[32] b1'[32] a2[32] b2'[32]
#define ZERO_FLOATS (8192u + 8192u + 136u)

__device__ __forceinline__ float elu_f(float x) { return x > 0.f ? x : (expf(x) - 1.f); }

__device__ __forceinline__ float wave_sum(float v) {
#pragma unroll
    for (int m = 1; m < 64; m <<= 1) v += __shfl_xor(v, m);
    return v;
}

// ---------- K1: pre-MLP (elu(elu(x@W1+b1)@W2+b2)) + BN1 stats ----------
__global__ __launch_bounds__(256) void k_pre(const float* __restrict__ x,
    const float* __restrict__ w1, const float* __restrict__ b1,
    const float* __restrict__ w2, const float* __restrict__ b2,
    float* __restrict__ h, float* __restrict__ stats)
{
    __shared__ float sw1[CIN * DD], sw2[DD * DD], sb1[DD], sb2[DD];
    int tid = threadIdx.x;
    for (int t = tid; t < CIN * DD; t += 256) sw1[t] = w1[t];
    for (int t = tid; t < DD * DD; t += 256) sw2[t] = w2[t];
    if (tid < DD) { sb1[tid] = b1[tid]; sb2[tid] = b2[tid]; }
    __syncthreads();

    int i = blockIdx.x * 256 + tid;
    float xr[CIN];
    const float4* xp = (const float4*)(x + (size_t)i * CIN);
#pragma unroll
    for (int t = 0; t < CIN / 4; ++t) {
        float4 v = xp[t];
        xr[4 * t] = v.x; xr[4 * t + 1] = v.y; xr[4 * t + 2] = v.z; xr[4 * t + 3] = v.w;
    }
    float t1[DD];
#pragma unroll
    for (int c = 0; c < DD; ++c) t1[c] = sb1[c];
#pragma unroll
    for (int k = 0; k < CIN; ++k) {
        float xv = xr[k];
#pragma unroll
        for (int c = 0; c < DD; ++c) t1[c] = fmaf(xv, sw1[k * DD + c], t1[c]);
    }
#pragma unroll
    for (int c = 0; c < DD; ++c) t1[c] = elu_f(t1[c]);
    float t2[DD];
#pragma unroll
    for (int c = 0; c < DD; ++c) t2[c] = sb2[c];
#pragma unroll
    for (int k = 0; k < DD; ++k) {
        float xv = t1[k];
#pragma unroll
        for (int c = 0; c < DD; ++c) t2[c] = fmaf(xv, sw2[k * DD + c], t2[c]);
    }
#pragma unroll
    for (int c = 0; c < DD; ++c) t2[c] = elu_f(t2[c]);

    float4* hp = (float4*)(h + (size_t)i * DD);
#pragma unroll
    for (int t = 0; t < DD / 4; ++t)
        hp[t] = make_float4(t2[4 * t], t2[4 * t + 1], t2[4 * t + 2], t2[4 * t + 3]);

    int lane = tid & 63;
#pragma unroll
    for (int c = 0; c < DD; ++c) {
        float s = wave_sum(t2[c]);
        float q = wave_sum(t2[c] * t2[c]);
        if (lane == 0) { atomicAdd(&stats[c], s); atomicAdd(&stats[DD + c], q); }
    }
}

// ---------- K2: finalize BN1 -> a1, b1' ----------
__global__ void k_bn1_fin(const float* __restrict__ stats, const float* __restrict__ g,
                          const float* __restrict__ b, float* __restrict__ ab)
{
    int c = threadIdx.x;
    if (c < DD) {
        float mean = stats[c] * (1.f / NPTS);
        float var = stats[DD + c] * (1.f / NPTS) - mean * mean;
        float a = g[c] * rsqrtf(var + 1e-5f);
        ab[c] = a;
        ab[DD + c] = b[c] - a * mean;
    }
}

// ---------- K3: x_in = BN(h); h_l = x_in@lin_h_w+b; s_l = x_in@lin_s_w ----------
__global__ __launch_bounds__(256) void k_proj(const float* __restrict__ h,
    const float* __restrict__ ab,
    const float* __restrict__ hw, const float* __restrict__ hb,
    const float* __restrict__ sw,
    float* __restrict__ xin, float* __restrict__ hl, float4* __restrict__ sl4)
{
    __shared__ float shw[DD * DD], ssw[DD * 3], sa[DD], sbp[DD], shb[DD];
    int tid = threadIdx.x;
    for (int t = tid; t < DD * DD; t += 256) shw[t] = hw[t];
    for (int t = tid; t < DD * 3; t += 256) ssw[t] = sw[t];
    if (tid < DD) { sa[tid] = ab[tid]; sbp[tid] = ab[DD + tid]; shb[tid] = hb[tid]; }
    __syncthreads();

    int i = blockIdx.x * 256 + tid;
    float r[DD];
    const float4* hp = (const float4*)(h + (size_t)i * DD);
#pragma unroll
    for (int t = 0; t < DD / 4; ++t) {
        float4 v = hp[t];
        r[4 * t] = v.x; r[4 * t + 1] = v.y; r[4 * t + 2] = v.z; r[4 * t + 3] = v.w;
    }
#pragma unroll
    for (int c = 0; c < DD; ++c) r[c] = fmaf(sa[c], r[c], sbp[c]);
    float4* xp = (float4*)(xin + (size_t)i * DD);
#pragma unroll
    for (int t = 0; t < DD / 4; ++t)
        xp[t] = make_float4(r[4 * t], r[4 * t + 1], r[4 * t + 2], r[4 * t + 3]);

    float o[DD];
#pragma unroll
    for (int c = 0; c < DD; ++c) o[c] = shb[c];
#pragma unroll
    for (int k = 0; k < DD; ++k) {
        float v = r[k];
#pragma unroll
        for (int c = 0; c < DD; ++c) o[c] = fmaf(v, shw[k * DD + c], o[c]);
    }
    float4* hlp = (float4*)(hl + (size_t)i * DD);
#pragma unroll
    for (int t = 0; t < DD / 4; ++t)
        hlp[t] = make_float4(o[4 * t], o[4 * t + 1], o[4 * t + 2], o[4 * t + 3]);

    float s0 = 0.f, s1 = 0.f, s2 = 0.f;
#pragma unroll
    for (int k = 0; k < DD; ++k) {
        float v = r[k];
        s0 = fmaf(v, ssw[k * 3 + 0], s0);
        s1 = fmaf(v, ssw[k * 3 + 1], s1);
        s2 = fmaf(v, ssw[k * 3 + 2], s2);
    }
    sl4[i] = make_float4(s0, s1, s2, 0.f);
}

// ---------- K4: brute-force kNN (top-40 smallest d2, self excluded) ----------
__global__ __launch_bounds__(64) void k_knn(const float4* __restrict__ sl4,
    int* __restrict__ idxo, float* __restrict__ esq,
    float* __restrict__ sumd, float* __restrict__ indeg)
{
    __shared__ float4 pts[NTILE];
    __shared__ float hd[KNN][64];
    __shared__ int hi[KNN][64];
    int tid = threadIdx.x;
    int i = blockIdx.x * 64 + tid;
    float4 q = sl4[i];
#pragma unroll
    for (int e = 0; e < KNN; ++e) { hd[e][tid] = INFINITY; hi[e][tid] = 0; }
    float curmax = INFINITY;
    int maxpos = 0;

    for (int tile = 0; tile < NPTS / NTILE; ++tile) {
        __syncthreads();
        for (int t = tid; t < NTILE; t += 64) pts[t] = sl4[tile * NTILE + t];
        __syncthreads();
        int base = tile * NTILE;
        for (int j = 0; j < NTILE; ++j) {
            float4 p = pts[j];
            float dx = q.x - p.x, dy = q.y - p.y, dz = q.z - p.z;
            float d2 = fmaf(dx, dx, fmaf(dy, dy, dz * dz));
            int jj = base + j;
            if (jj != i && d2 < curmax) {
                hd[maxpos][tid] = d2;
                hi[maxpos][tid] = jj;
                float m = hd[0][tid];
                int mp = 0;
#pragma unroll 8
                for (int e = 1; e < KNN; ++e) {
                    float v = hd[e][tid];
                    if (v > m) { m = v; mp = e; }
                }
                curmax = m; maxpos = mp;
            }
        }
    }

    int rb = i * KNN;
#pragma unroll
    for (int e = 0; e < KNN; ++e) {
        int j = hi[e][tid];
        float d2 = fmaxf(hd[e][tid], 0.f);
        idxo[rb + e] = j;
        esq[rb + e] = d2;
        float dist = sqrtf(d2 + 1e-6f);
        atomicAdd(&sumd[j], dist);
        atomicAdd(&indeg[j], 1.0f);
    }
}

// ---------- K5: loss_regularizing_neig accumulation ----------
__global__ __launch_bounds__(256) void k_loss1(const float* __restrict__ sumd,
    const float* __restrict__ indeg, float* __restrict__ stats)
{
    int i = blockIdx.x * 256 + threadIdx.x;
    float id = indeg[i], sd = sumd[i];
    float av = id > 0.f ? sd / fmaxf(id, 1.f) : 0.f;
    float t = av - 0.5f;
    float v = wave_sum(t * t);
    if ((threadIdx.x & 63) == 0) atomicAdd(&stats[128], v);
}

// ---------- K6: gather/aggregate + lin + post-MLP + BN2 stats + loss2 ----------
__global__ __launch_bounds__(256) void k_agg(
    const int* __restrict__ idx, const float* __restrict__ esq,
    const float* __restrict__ hl, const float* __restrict__ xin,
    const float4* __restrict__ sl4, const float* __restrict__ sumd,
    const float* __restrict__ lw, const float* __restrict__ lb,
    const float* __restrict__ pw1, const float* __restrict__ pb1,
    const float* __restrict__ pw2, const float* __restrict__ pb2,
    float* __restrict__ o, float* __restrict__ stats)
{
    __shared__ float slw[96 * DD], spw1[67 * DD], spw2[DD * DD], slb[DD], spb1[DD], spb2[DD];
    int tid = threadIdx.x;
    for (int t = tid; t < 96 * DD; t += 256) slw[t] = lw[t];
    for (int t = tid; t < 67 * DD; t += 256) spw1[t] = pw1[t];
    for (int t = tid; t < DD * DD; t += 256) spw2[t] = pw2[t];
    if (tid < DD) { slb[tid] = lb[tid]; spb1[tid] = pb1[tid]; spb2[tid] = pb2[tid]; }
    __syncthreads();

    int i = blockIdx.x * 256 + tid;
    float sv[DD], mv[DD];
#pragma unroll
    for (int c = 0; c < DD; ++c) { sv[c] = 0.f; mv[c] = -INFINITY; }
    float l2 = 0.f;
    int rb = i * KNN;
#pragma unroll 2
    for (int k = 0; k < KNN; ++k) {
        int j = idx[rb + k];
        float w = esq[rb + k];
        float dist = sqrtf(w + 1e-6f);
        float sd = sumd[j];
        float nrm = dist / (sd + 1e-4f);
        float dg = sd / (sd + 1e-4f) + 1e-4f;   // degs2[j] closed form
        float gn = dist / dg;
        float ddf = nrm - gn;
        l2 += ddf * ddf;
        const float4* hp = (const float4*)(hl + (size_t)j * DD);
#pragma unroll
        for (int t = 0; t < DD / 4; ++t) {
            float4 hv = hp[t];
            float m0 = hv.x * w, m1 = hv.y * w, m2 = hv.z * w, m3 = hv.w * w;
            sv[4 * t] += m0; sv[4 * t + 1] += m1; sv[4 * t + 2] += m2; sv[4 * t + 3] += m3;
            mv[4 * t] = fmaxf(mv[4 * t], m0);
            mv[4 * t + 1] = fmaxf(mv[4 * t + 1], m1);
            mv[4 * t + 2] = fmaxf(mv[4 * t + 2], m2);
            mv[4 * t + 3] = fmaxf(mv[4 * t + 3], m3);
        }
    }

    float xr[DD];
    const float4* xp = (const float4*)(xin + (size_t)i * DD);
#pragma unroll
    for (int t = 0; t < DD / 4; ++t) {
        float4 v = xp[t];
        xr[4 * t] = v.x; xr[4 * t + 1] = v.y; xr[4 * t + 2] = v.z; xr[4 * t + 3] = v.w;
    }

    float xg[DD];
#pragma unroll
    for (int c = 0; c < DD; ++c) xg[c] = slb[c];
#pragma unroll
    for (int k = 0; k < DD; ++k) {
        float m = sv[k] * (1.f / KNN);
#pragma unroll
        for (int c = 0; c < DD; ++c) xg[c] = fmaf(m, slw[k * DD + c], xg[c]);
    }
#pragma unroll
    for (int k = 0; k < DD; ++k) {
        float m = mv[k];
#pragma unroll
        for (int c = 0; c < DD; ++c) xg[c] = fmaf(m, slw[(DD + k) * DD + c], xg[c]);
    }
#pragma unroll
    for (int k = 0; k < DD; ++k) {
        float m = xr[k];
#pragma unroll
        for (int c = 0; c < DD; ++c) xg[c] = fmaf(m, slw[(2 * DD + k) * DD + c], xg[c]);
    }

    float4 sl = sl4[i];
    float o1[DD];
#pragma unroll
    for (int c = 0; c < DD; ++c) o1[c] = spb1[c];
#pragma unroll
    for (int k = 0; k < DD; ++k) {
        float m = xg[k];
#pragma unroll
        for (int c = 0; c < DD; ++c) o1[c] = fmaf(m, spw1[k * DD + c], o1[c]);
    }
#pragma unroll
    for (int c = 0; c < DD; ++c) {
        o1[c] = fmaf(sl.x, spw1[32 * DD + c], o1[c]);
        o1[c] = fmaf(sl.y, spw1[33 * DD + c], o1[c]);
        o1[c] = fmaf(sl.z, spw1[34 * DD + c], o1[c]);
    }
#pragma unroll
    for (int k = 0; k < DD; ++k) {
        float m = xr[k];
#pragma unroll
        for (int c = 0; c < DD; ++c) o1[c] = fmaf(m, spw1[(35 + k) * DD + c], o1[c]);
    }
#pragma unroll
    for (int c = 0; c < DD; ++c) o1[c] = elu_f(o1[c]);

    float o2[DD];
#pragma unroll
    for (int c = 0; c < DD; ++c) o2[c] = spb2[c];
#pragma unroll
    for (int k = 0; k < DD; ++k) {
        float m = o1[k];
#pragma unroll
        for (int c = 0; c < DD; ++c) o2[c] = fmaf(m, spw2[k * DD + c], o2[c]);
    }
#pragma unroll
    for (int c = 0; c < DD; ++c) o2[c] = elu_f(o2[c]);

    float4* op = (float4*)(o + (size_t)i * DD);
#pragma unroll
    for (int t = 0; t < DD / 4; ++t)
        op[t] = make_float4(o2[4 * t], o2[4 * t + 1], o2[4 * t + 2], o2[4 * t + 3]);

    int lane = tid & 63;
#pragma unroll
    for (int c = 0; c < DD; ++c) {
        float s = wave_sum(o2[c]);
        float q = wave_sum(o2[c] * o2[c]);
        if (lane == 0) { atomicAdd(&stats[64 + c], s); atomicAdd(&stats[96 + c], q); }
    }
    float l2s = wave_sum(l2);
    if (lane == 0) atomicAdd(&stats[129], l2s);
}

// ---------- K7: finalize BN2 + write both losses ----------
__global__ void k_fin(const float* __restrict__ stats, const float* __restrict__ g,
                      const float* __restrict__ b, float* __restrict__ ab,
                      float* __restrict__ dout)
{
    int c = threadIdx.x;
    if (c < DD) {
        float mean = stats[64 + c] * (1.f / NPTS);
        float var = stats[96 + c] * (1.f / NPTS) - mean * mean;
        float a = g[c] * rsqrtf(var + 1e-5f);
        ab[64 + c] = a;
        ab[96 + c] = b[c] - a * mean;
    }
    if (c == 32) dout[NPTS * DD] = 0.01f * stats[128] * (1.f / NPTS);
    if (c == 33) dout[NPTS * DD + 1] = 0.1f * stats[129] * (1.f / ((float)NPTS * KNN));
}

// ---------- K8: out = a2*o + b2' ----------
__global__ __launch_bounds__(256) void k_out(const float* __restrict__ o,
    const float* __restrict__ ab, float* __restrict__ dout)
{
    int t = blockIdx.x * 256 + threadIdx.x;
    int c = t & (DD - 1);
    dout[t] = fmaf(ab[64 + c], o[t], ab[96 + c]);
}

extern "C" void kernel_launch(void* const* d_in, const int* in_sizes, int n_in,
                              void* d_out, int out_size, void* d_ws, size_t ws_size,
                              hipStream_t stream)
{
    (void)in_sizes; (void)n_in; (void)out_size; (void)ws_size;
    const float* x      = (const float*)d_in[0];
    const float* pre_w1 = (const float*)d_in[5];
    const float* pre_b1 = (const float*)d_in[6];
    const float* pre_w2 = (const float*)d_in[7];
    const float* pre_b2 = (const float*)d_in[8];
    const float* bn1_g  = (const float*)d_in[9];
    const float* bn1_b  = (const float*)d_in[10];
    const float* lin_s_w = (const float*)d_in[11];
    const float* lin_h_w = (const float*)d_in[12];
    const float* lin_h_b = (const float*)d_in[13];
    const float* lin_w   = (const float*)d_in[14];
    const float* lin_b   = (const float*)d_in[15];
    const float* post_w1 = (const float*)d_in[16];
    const float* post_b1 = (const float*)d_in[17];
    const float* post_w2 = (const float*)d_in[18];
    const float* post_b2 = (const float*)d_in[19];
    const float* bn2_g   = (const float*)d_in[20];
    const float* bn2_b   = (const float*)d_in[21];

    float* W = (float*)d_ws;
    float* h     = W + OFF_H;
    float* xin   = W + OFF_XIN;
    float* hl    = W + OFF_HL;
    float4* sl4  = (float4*)(W + OFF_SL);
    float* esq   = W + OFF_ESQ;
    float* o     = W + OFF_O;
    int*   idx   = (int*)(W + OFF_IDX);
    float* sumd  = W + OFF_SUMD;
    float* indeg = W + OFF_INDEG;
    float* stats = W + OFF_STATS;
    float* ab    = W + OFF_AB;
    float* dout  = (float*)d_out;

    // zero accumulators (sumd, indeg, stats are contiguous)
    hipMemsetAsync(W + OFF_SUMD, 0, ZERO_FLOATS * sizeof(float), stream);

    k_pre<<<NPTS / 256, 256, 0, stream>>>(x, pre_w1, pre_b1, pre_w2, pre_b2, h, stats);
    k_bn1_fin<<<1, 32, 0, stream>>>(stats, bn1_g, bn1_b, ab);
    k_proj<<<NPTS / 256, 256, 0, stream>>>(h, ab, lin_h_w, lin_h_b, lin_s_w, xin, hl, sl4);
    k_knn<<<NPTS / 64, 64, 0, stream>>>(sl4, idx, esq, sumd, indeg);
    k_loss1<<<NPTS / 256, 256, 0, stream>>>(sumd, indeg, stats);
    k_agg<<<NPTS / 256, 256, 0, stream>>>(idx, esq, hl, xin, sl4, sumd,
                                          lin_w, lin_b, post_w1, post_b1, post_w2, post_b2,
                                          o, stats);
    k_fin<<<1, 64, 0, stream>>>(stats, bn2_g, bn2_b, ab, dout);
    k_out<<<NPTS * DD / 256, 256, 0, stream>>>(o, ab, dout);
}

// Round 2
// 365.779 us; speedup vs baseline: 12.4785x; 12.4785x over previous
//
#include <hip/hip_runtime.h>
#include <math.h>

#define NPTS 8192
#define KNN 40
#define DD 32
#define CIN 16

// ---- ws layout (float offsets) ----
#define OFF_H      0u         // 8192*32
#define OFF_XIN    262144u    // 8192*32
#define OFF_HL     524288u    // 8192*32
#define OFF_SL     786432u    // 8192*4 (float4)
#define OFF_ESQ    819200u    // 8192*40
#define OFF_O      1146880u   // 8192*32
#define OFF_IDX    1409024u   // 8192*40 (int)
#define OFF_SUMD   1736704u   // 8192
#define OFF_INDEG  1744896u   // 8192
#define OFF_STATS  1753088u   // 136: bn1 s[32] ss[32], bn2 s[32] ss[32], loss1, loss2
#define OFF_AB     1753224u   // 128: a1[32] b1'[32] a2[32] b2'[32]
#define ZERO_FLOATS (8192u + 8192u + 136u)

__device__ __forceinline__ float elu_f(float x) { return x > 0.f ? x : (expf(x) - 1.f); }

__device__ __forceinline__ float wave_sum(float v) {
#pragma unroll
    for (int m = 1; m < 64; m <<= 1) v += __shfl_xor(v, m);
    return v;
}

// ---------- K1: pre-MLP (elu(elu(x@W1+b1)@W2+b2)) + BN1 stats ----------
__global__ __launch_bounds__(256) void k_pre(const float* __restrict__ x,
    const float* __restrict__ w1, const float* __restrict__ b1,
    const float* __restrict__ w2, const float* __restrict__ b2,
    float* __restrict__ h, float* __restrict__ stats)
{
    __shared__ float sw1[CIN * DD], sw2[DD * DD], sb1[DD], sb2[DD];
    int tid = threadIdx.x;
    for (int t = tid; t < CIN * DD; t += 256) sw1[t] = w1[t];
    for (int t = tid; t < DD * DD; t += 256) sw2[t] = w2[t];
    if (tid < DD) { sb1[tid] = b1[tid]; sb2[tid] = b2[tid]; }
    __syncthreads();

    int i = blockIdx.x * 256 + tid;
    float xr[CIN];
    const float4* xp = (const float4*)(x + (size_t)i * CIN);
#pragma unroll
    for (int t = 0; t < CIN / 4; ++t) {
        float4 v = xp[t];
        xr[4 * t] = v.x; xr[4 * t + 1] = v.y; xr[4 * t + 2] = v.z; xr[4 * t + 3] = v.w;
    }
    float t1[DD];
#pragma unroll
    for (int c = 0; c < DD; ++c) t1[c] = sb1[c];
#pragma unroll
    for (int k = 0; k < CIN; ++k) {
        float xv = xr[k];
#pragma unroll
        for (int c = 0; c < DD; ++c) t1[c] = fmaf(xv, sw1[k * DD + c], t1[c]);
    }
#pragma unroll
    for (int c = 0; c < DD; ++c) t1[c] = elu_f(t1[c]);
    float t2[DD];
#pragma unroll
    for (int c = 0; c < DD; ++c) t2[c] = sb2[c];
#pragma unroll
    for (int k = 0; k < DD; ++k) {
        float xv = t1[k];
#pragma unroll
        for (int c = 0; c < DD; ++c) t2[c] = fmaf(xv, sw2[k * DD + c], t2[c]);
    }
#pragma unroll
    for (int c = 0; c < DD; ++c) t2[c] = elu_f(t2[c]);

    float4* hp = (float4*)(h + (size_t)i * DD);
#pragma unroll
    for (int t = 0; t < DD / 4; ++t)
        hp[t] = make_float4(t2[4 * t], t2[4 * t + 1], t2[4 * t + 2], t2[4 * t + 3]);

    int lane = tid & 63;
#pragma unroll
    for (int c = 0; c < DD; ++c) {
        float s = wave_sum(t2[c]);
        float q = wave_sum(t2[c] * t2[c]);
        if (lane == 0) { atomicAdd(&stats[c], s); atomicAdd(&stats[DD + c], q); }
    }
}

// ---------- K2: finalize BN1 -> a1, b1' ----------
__global__ void k_bn1_fin(const float* __restrict__ stats, const float* __restrict__ g,
                          const float* __restrict__ b, float* __restrict__ ab)
{
    int c = threadIdx.x;
    if (c < DD) {
        float mean = stats[c] * (1.f / NPTS);
        float var = stats[DD + c] * (1.f / NPTS) - mean * mean;
        float a = g[c] * rsqrtf(var + 1e-5f);
        ab[c] = a;
        ab[DD + c] = b[c] - a * mean;
    }
}

// ---------- K3: x_in = BN(h); h_l = x_in@lin_h_w+b; s_l = x_in@lin_s_w ----------
__global__ __launch_bounds__(256) void k_proj(const float* __restrict__ h,
    const float* __restrict__ ab,
    const float* __restrict__ hw, const float* __restrict__ hb,
    const float* __restrict__ sw,
    float* __restrict__ xin, float* __restrict__ hl, float4* __restrict__ sl4)
{
    __shared__ float shw[DD * DD], ssw[DD * 3], sa[DD], sbp[DD], shb[DD];
    int tid = threadIdx.x;
    for (int t = tid; t < DD * DD; t += 256) shw[t] = hw[t];
    for (int t = tid; t < DD * 3; t += 256) ssw[t] = sw[t];
    if (tid < DD) { sa[tid] = ab[tid]; sbp[tid] = ab[DD + tid]; shb[tid] = hb[tid]; }
    __syncthreads();

    int i = blockIdx.x * 256 + tid;
    float r[DD];
    const float4* hp = (const float4*)(h + (size_t)i * DD);
#pragma unroll
    for (int t = 0; t < DD / 4; ++t) {
        float4 v = hp[t];
        r[4 * t] = v.x; r[4 * t + 1] = v.y; r[4 * t + 2] = v.z; r[4 * t + 3] = v.w;
    }
#pragma unroll
    for (int c = 0; c < DD; ++c) r[c] = fmaf(sa[c], r[c], sbp[c]);
    float4* xp = (float4*)(xin + (size_t)i * DD);
#pragma unroll
    for (int t = 0; t < DD / 4; ++t)
        xp[t] = make_float4(r[4 * t], r[4 * t + 1], r[4 * t + 2], r[4 * t + 3]);

    float o[DD];
#pragma unroll
    for (int c = 0; c < DD; ++c) o[c] = shb[c];
#pragma unroll
    for (int k = 0; k < DD; ++k) {
        float v = r[k];
#pragma unroll
        for (int c = 0; c < DD; ++c) o[c] = fmaf(v, shw[k * DD + c], o[c]);
    }
    float4* hlp = (float4*)(hl + (size_t)i * DD);
#pragma unroll
    for (int t = 0; t < DD / 4; ++t)
        hlp[t] = make_float4(o[4 * t], o[4 * t + 1], o[4 * t + 2], o[4 * t + 3]);

    float s0 = 0.f, s1 = 0.f, s2 = 0.f;
#pragma unroll
    for (int k = 0; k < DD; ++k) {
        float v = r[k];
        s0 = fmaf(v, ssw[k * 3 + 0], s0);
        s1 = fmaf(v, ssw[k * 3 + 1], s1);
        s2 = fmaf(v, ssw[k * 3 + 2], s2);
    }
    sl4[i] = make_float4(s0, s1, s2, 0.f);
}

// ---------- K4: brute-force kNN — one wave per query, lane-sorted top-40 ----------
// Lane l (l<40) holds the l-th smallest (d2, idx) seen so far, in registers.
// Insert loop is wave-uniform (scalar walk of the ballot mask) -> no divergence.
__global__ __launch_bounds__(256) void k_knn(const float4* __restrict__ sl4,
    int* __restrict__ idxo, float* __restrict__ esq,
    float* __restrict__ sumd, float* __restrict__ indeg)
{
    int lane = threadIdx.x & 63;
    int i = blockIdx.x * 4 + (threadIdx.x >> 6);   // query for this wave
    float4 q = sl4[i];

    float h_d = INFINITY;   // sorted ascending across lanes 0..39
    int   h_i = 0;
    float thr = INFINITY;   // current 40th-smallest (lane 39's h_d)

    for (int base = 0; base < NPTS; base += 64) {
        int j = base + lane;
        float4 p = sl4[j];
        float dx = q.x - p.x, dy = q.y - p.y, dz = q.z - p.z;
        float d2 = fmaf(dx, dx, fmaf(dy, dy, dz * dz));
        if (j == i) d2 = INFINITY;                 // self-exclusion
        unsigned long long m = __ballot(d2 < thr);
        while (m) {
            int src = __ffsll(m) - 1;
            m &= m - 1;
            float db = __shfl(d2, src);            // uniform broadcast
            if (db < thr) {                        // thr may have tightened
                int jb = base + src;
                unsigned long long pm = __ballot(db < h_d) & 0xFFFFFFFFFFull;
                int pos = __ffsll(pm) - 1;         // 0..39 guaranteed (db < thr)
                float sh = __shfl_up(h_d, 1);
                int   si = __shfl_up(h_i, 1);
                bool seg = (lane > pos) && (lane < KNN);
                h_d = (lane == pos) ? db : (seg ? sh : h_d);
                h_i = (lane == pos) ? jb : (seg ? si : h_i);
                thr = __shfl(h_d, KNN - 1);
            }
        }
    }

    if (lane < KNN) {
        int rb = i * KNN + lane;
        idxo[rb] = h_i;
        esq[rb] = h_d;                             // >= 0 by construction
        float dist = sqrtf(h_d + 1e-6f);
        atomicAdd(&sumd[h_i], dist);
        atomicAdd(&indeg[h_i], 1.0f);
    }
}

// ---------- K5: loss_regularizing_neig accumulation ----------
__global__ __launch_bounds__(256) void k_loss1(const float* __restrict__ sumd,
    const float* __restrict__ indeg, float* __restrict__ stats)
{
    int i = blockIdx.x * 256 + threadIdx.x;
    float id = indeg[i], sd = sumd[i];
    float av = id > 0.f ? sd / fmaxf(id, 1.f) : 0.f;
    float t = av - 0.5f;
    float v = wave_sum(t * t);
    if ((threadIdx.x & 63) == 0) atomicAdd(&stats[128], v);
}

// ---------- K6: gather/aggregate + lin + post-MLP + BN2 stats + loss2 ----------
__global__ __launch_bounds__(256) void k_agg(
    const int* __restrict__ idx, const float* __restrict__ esq,
    const float* __restrict__ hl, const float* __restrict__ xin,
    const float4* __restrict__ sl4, const float* __restrict__ sumd,
    const float* __restrict__ lw, const float* __restrict__ lb,
    const float* __restrict__ pw1, const float* __restrict__ pb1,
    const float* __restrict__ pw2, const float* __restrict__ pb2,
    float* __restrict__ o, float* __restrict__ stats)
{
    __shared__ float slw[96 * DD], spw1[67 * DD], spw2[DD * DD], slb[DD], spb1[DD], spb2[DD];
    int tid = threadIdx.x;
    for (int t = tid; t < 96 * DD; t += 256) slw[t] = lw[t];
    for (int t = tid; t < 67 * DD; t += 256) spw1[t] = pw1[t];
    for (int t = tid; t < DD * DD; t += 256) spw2[t] = pw2[t];
    if (tid < DD) { slb[tid] = lb[tid]; spb1[tid] = pb1[tid]; spb2[tid] = pb2[tid]; }
    __syncthreads();

    int i = blockIdx.x * 256 + tid;
    float sv[DD], mv[DD];
#pragma unroll
    for (int c = 0; c < DD; ++c) { sv[c] = 0.f; mv[c] = -INFINITY; }
    float l2 = 0.f;
    int rb = i * KNN;
#pragma unroll 2
    for (int k = 0; k < KNN; ++k) {
        int j = idx[rb + k];
        float w = esq[rb + k];
        float dist = sqrtf(w + 1e-6f);
        float sd = sumd[j];
        float nrm = dist / (sd + 1e-4f);
        float dg = sd / (sd + 1e-4f) + 1e-4f;   // degs2[j] closed form
        float gn = dist / dg;
        float ddf = nrm - gn;
        l2 += ddf * ddf;
        const float4* hp = (const float4*)(hl + (size_t)j * DD);
#pragma unroll
        for (int t = 0; t < DD / 4; ++t) {
            float4 hv = hp[t];
            float m0 = hv.x * w, m1 = hv.y * w, m2 = hv.z * w, m3 = hv.w * w;
            sv[4 * t] += m0; sv[4 * t + 1] += m1; sv[4 * t + 2] += m2; sv[4 * t + 3] += m3;
            mv[4 * t] = fmaxf(mv[4 * t], m0);
            mv[4 * t + 1] = fmaxf(mv[4 * t + 1], m1);
            mv[4 * t + 2] = fmaxf(mv[4 * t + 2], m2);
            mv[4 * t + 3] = fmaxf(mv[4 * t + 3], m3);
        }
    }

    float xr[DD];
    const float4* xp = (const float4*)(xin + (size_t)i * DD);
#pragma unroll
    for (int t = 0; t < DD / 4; ++t) {
        float4 v = xp[t];
        xr[4 * t] = v.x; xr[4 * t + 1] = v.y; xr[4 * t + 2] = v.z; xr[4 * t + 3] = v.w;
    }

    float xg[DD];
#pragma unroll
    for (int c = 0; c < DD; ++c) xg[c] = slb[c];
#pragma unroll
    for (int k = 0; k < DD; ++k) {
        float m = sv[k] * (1.f / KNN);
#pragma unroll
        for (int c = 0; c < DD; ++c) xg[c] = fmaf(m, slw[k * DD + c], xg[c]);
    }
#pragma unroll
    for (int k = 0; k < DD; ++k) {
        float m = mv[k];
#pragma unroll
        for (int c = 0; c < DD; ++c) xg[c] = fmaf(m, slw[(DD + k) * DD + c], xg[c]);
    }
#pragma unroll
    for (int k = 0; k < DD; ++k) {
        float m = xr[k];
#pragma unroll
        for (int c = 0; c < DD; ++c) xg[c] = fmaf(m, slw[(2 * DD + k) * DD + c], xg[c]);
    }

    float4 sl = sl4[i];
    float o1[DD];
#pragma unroll
    for (int c = 0; c < DD; ++c) o1[c] = spb1[c];
#pragma unroll
    for (int k = 0; k < DD; ++k) {
        float m = xg[k];
#pragma unroll
        for (int c = 0; c < DD; ++c) o1[c] = fmaf(m, spw1[k * DD + c], o1[c]);
    }
#pragma unroll
    for (int c = 0; c < DD; ++c) {
        o1[c] = fmaf(sl.x, spw1[32 * DD + c], o1[c]);
        o1[c] = fmaf(sl.y, spw1[33 * DD + c], o1[c]);
        o1[c] = fmaf(sl.z, spw1[34 * DD + c], o1[c]);
    }
#pragma unroll
    for (int k = 0; k < DD; ++k) {
        float m = xr[k];
#pragma unroll
        for (int c = 0; c < DD; ++c) o1[c] = fmaf(m, spw1[(35 + k) * DD + c], o1[c]);
    }
#pragma unroll
    for (int c = 0; c < DD; ++c) o1[c] = elu_f(o1[c]);

    float o2[DD];
#pragma unroll
    for (int c = 0; c < DD; ++c) o2[c] = spb2[c];
#pragma unroll
    for (int k = 0; k < DD; ++k) {
        float m = o1[k];
#pragma unroll
        for (int c = 0; c < DD; ++c) o2[c] = fmaf(m, spw2[k * DD + c], o2[c]);
    }
#pragma unroll
    for (int c = 0; c < DD; ++c) o2[c] = elu_f(o2[c]);

    float4* op = (float4*)(o + (size_t)i * DD);
#pragma unroll
    for (int t = 0; t < DD / 4; ++t)
        op[t] = make_float4(o2[4 * t], o2[4 * t + 1], o2[4 * t + 2], o2[4 * t + 3]);

    int lane = tid & 63;
#pragma unroll
    for (int c = 0; c < DD; ++c) {
        float s = wave_sum(o2[c]);
        float q = wave_sum(o2[c] * o2[c]);
        if (lane == 0) { atomicAdd(&stats[64 + c], s); atomicAdd(&stats[96 + c], q); }
    }
    float l2s = wave_sum(l2);
    if (lane == 0) atomicAdd(&stats[129], l2s);
}

// ---------- K7: finalize BN2 + write both losses ----------
__global__ void k_fin(const float* __restrict__ stats, const float* __restrict__ g,
                      const float* __restrict__ b, float* __restrict__ ab,
                      float* __restrict__ dout)
{
    int c = threadIdx.x;
    if (c < DD) {
        float mean = stats[64 + c] * (1.f / NPTS);
        float var = stats[96 + c] * (1.f / NPTS) - mean * mean;
        float a = g[c] * rsqrtf(var + 1e-5f);
        ab[64 + c] = a;
        ab[96 + c] = b[c] - a * mean;
    }
    if (c == 32) dout[NPTS * DD] = 0.01f * stats[128] * (1.f / NPTS);
    if (c == 33) dout[NPTS * DD + 1] = 0.1f * stats[129] * (1.f / ((float)NPTS * KNN));
}

// ---------- K8: out = a2*o + b2' ----------
__global__ __launch_bounds__(256) void k_out(const float* __restrict__ o,
    const float* __restrict__ ab, float* __restrict__ dout)
{
    int t = blockIdx.x * 256 + threadIdx.x;
    int c = t & (DD - 1);
    dout[t] = fmaf(ab[64 + c], o[t], ab[96 + c]);
}

extern "C" void kernel_launch(void* const* d_in, const int* in_sizes, int n_in,
                              void* d_out, int out_size, void* d_ws, size_t ws_size,
                              hipStream_t stream)
{
    (void)in_sizes; (void)n_in; (void)out_size; (void)ws_size;
    const float* x      = (const float*)d_in[0];
    const float* pre_w1 = (const float*)d_in[5];
    const float* pre_b1 = (const float*)d_in[6];
    const float* pre_w2 = (const float*)d_in[7];
    const float* pre_b2 = (const float*)d_in[8];
    const float* bn1_g  = (const float*)d_in[9];
    const float* bn1_b  = (const float*)d_in[10];
    const float* lin_s_w = (const float*)d_in[11];
    const float* lin_h_w = (const float*)d_in[12];
    const float* lin_h_b = (const float*)d_in[13];
    const float* lin_w   = (const float*)d_in[14];
    const float* lin_b   = (const float*)d_in[15];
    const float* post_w1 = (const float*)d_in[16];
    const float* post_b1 = (const float*)d_in[17];
    const float* post_w2 = (const float*)d_in[18];
    const float* post_b2 = (const float*)d_in[19];
    const float* bn2_g   = (const float*)d_in[20];
    const float* bn2_b   = (const float*)d_in[21];

    float* W = (float*)d_ws;
    float* h     = W + OFF_H;
    float* xin   = W + OFF_XIN;
    float* hl    = W + OFF_HL;
    float4* sl4  = (float4*)(W + OFF_SL);
    float* esq   = W + OFF_ESQ;
    float* o     = W + OFF_O;
    int*   idx   = (int*)(W + OFF_IDX);
    float* sumd  = W + OFF_SUMD;
    float* indeg = W + OFF_INDEG;
    float* stats = W + OFF_STATS;
    float* ab    = W + OFF_AB;
    float* dout  = (float*)d_out;

    // zero accumulators (sumd, indeg, stats are contiguous)
    hipMemsetAsync(W + OFF_SUMD, 0, ZERO_FLOATS * sizeof(float), stream);

    k_pre<<<NPTS / 256, 256, 0, stream>>>(x, pre_w1, pre_b1, pre_w2, pre_b2, h, stats);
    k_bn1_fin<<<1, 32, 0, stream>>>(stats, bn1_g, bn1_b, ab);
    k_proj<<<NPTS / 256, 256, 0, stream>>>(h, ab, lin_h_w, lin_h_b, lin_s_w, xin, hl, sl4);
    k_knn<<<NPTS / 4, 256, 0, stream>>>(sl4, idx, esq, sumd, indeg);
    k_loss1<<<NPTS / 256, 256, 0, stream>>>(sumd, indeg, stats);
    k_agg<<<NPTS / 256, 256, 0, stream>>>(idx, esq, hl, xin, sl4, sumd,
                                          lin_w, lin_b, post_w1, post_b1, post_w2, post_b2,
                                          o, stats);
    k_fin<<<1, 64, 0, stream>>>(stats, bn2_g, bn2_b, ab, dout);
    k_out<<<NPTS * DD / 256, 256, 0, stream>>>(o, ab, dout);
}

// Round 3
// 310.697 us; speedup vs baseline: 14.6907x; 1.1773x over previous
//
#include <hip/hip_runtime.h>
#include <math.h>

#define NPTS 8192
#define KNN 40
#define DD 32
#define CIN 16
#define EDGES (NPTS * KNN)

// ---- ws layout (float offsets) ----
#define OFF_H      0u         // 8192*32
#define OFF_XIN    262144u    // 8192*32
#define OFF_HL     524288u    // 8192*32
#define OFF_SL     786432u    // 8192*4 (float4)
#define OFF_ESQ    819200u    // 8192*40
#define OFF_O      1146880u   // 8192*32
#define OFF_IDX    1409024u   // 8192*40 (int)
#define OFF_SUMD   1736704u   // 8192
#define OFF_INDEG  1744896u   // 8192
#define OFF_STATS  1753088u   // 136: bn1 s[32] ss[32], bn2 s[32] ss[32], loss1, loss2
#define OFF_AB     1753224u   // 128: a1[32] b1'[32] a2[32] b2'[32]
#define ZERO_FLOATS (8192u + 8192u + 136u)

__device__ __forceinline__ float elu_f(float x) { return x > 0.f ? x : (expf(x) - 1.f); }

__device__ __forceinline__ float wave_sum(float v) {
#pragma unroll
    for (int m = 1; m < 64; m <<= 1) v += __shfl_xor(v, m);
    return v;
}

// ---------- K1: pre-MLP (elu(elu(x@W1+b1)@W2+b2)) + BN1 stats ----------
__global__ __launch_bounds__(256) void k_pre(const float* __restrict__ x,
    const float* __restrict__ w1, const float* __restrict__ b1,
    const float* __restrict__ w2, const float* __restrict__ b2,
    float* __restrict__ h, float* __restrict__ stats)
{
    __shared__ float sw1[CIN * DD], sw2[DD * DD], sb1[DD], sb2[DD];
    int tid = threadIdx.x;
    for (int t = tid; t < CIN * DD; t += 256) sw1[t] = w1[t];
    for (int t = tid; t < DD * DD; t += 256) sw2[t] = w2[t];
    if (tid < DD) { sb1[tid] = b1[tid]; sb2[tid] = b2[tid]; }
    __syncthreads();

    int i = blockIdx.x * 256 + tid;
    float xr[CIN];
    const float4* xp = (const float4*)(x + (size_t)i * CIN);
#pragma unroll
    for (int t = 0; t < CIN / 4; ++t) {
        float4 v = xp[t];
        xr[4 * t] = v.x; xr[4 * t + 1] = v.y; xr[4 * t + 2] = v.z; xr[4 * t + 3] = v.w;
    }
    float t1[DD];
#pragma unroll
    for (int c = 0; c < DD; ++c) t1[c] = sb1[c];
#pragma unroll
    for (int k = 0; k < CIN; ++k) {
        float xv = xr[k];
#pragma unroll
        for (int c = 0; c < DD; ++c) t1[c] = fmaf(xv, sw1[k * DD + c], t1[c]);
    }
#pragma unroll
    for (int c = 0; c < DD; ++c) t1[c] = elu_f(t1[c]);
    float t2[DD];
#pragma unroll
    for (int c = 0; c < DD; ++c) t2[c] = sb2[c];
#pragma unroll
    for (int k = 0; k < DD; ++k) {
        float xv = t1[k];
#pragma unroll
        for (int c = 0; c < DD; ++c) t2[c] = fmaf(xv, sw2[k * DD + c], t2[c]);
    }
#pragma unroll
    for (int c = 0; c < DD; ++c) t2[c] = elu_f(t2[c]);

    float4* hp = (float4*)(h + (size_t)i * DD);
#pragma unroll
    for (int t = 0; t < DD / 4; ++t)
        hp[t] = make_float4(t2[4 * t], t2[4 * t + 1], t2[4 * t + 2], t2[4 * t + 3]);

    int lane = tid & 63;
#pragma unroll
    for (int c = 0; c < DD; ++c) {
        float s = wave_sum(t2[c]);
        float q = wave_sum(t2[c] * t2[c]);
        if (lane == 0) { atomicAdd(&stats[c], s); atomicAdd(&stats[DD + c], q); }
    }
}

// ---------- K2: finalize BN1 -> a1, b1' ----------
__global__ void k_bn1_fin(const float* __restrict__ stats, const float* __restrict__ g,
                          const float* __restrict__ b, float* __restrict__ ab)
{
    int c = threadIdx.x;
    if (c < DD) {
        float mean = stats[c] * (1.f / NPTS);
        float var = stats[DD + c] * (1.f / NPTS) - mean * mean;
        float a = g[c] * rsqrtf(var + 1e-5f);
        ab[c] = a;
        ab[DD + c] = b[c] - a * mean;
    }
}

// ---------- K3: x_in = BN(h); h_l = x_in@lin_h_w+b; s_l = x_in@lin_s_w ----------
__global__ __launch_bounds__(256) void k_proj(const float* __restrict__ h,
    const float* __restrict__ ab,
    const float* __restrict__ hw, const float* __restrict__ hb,
    const float* __restrict__ sw,
    float* __restrict__ xin, float* __restrict__ hl, float4* __restrict__ sl4)
{
    __shared__ float shw[DD * DD], ssw[DD * 3], sa[DD], sbp[DD], shb[DD];
    int tid = threadIdx.x;
    for (int t = tid; t < DD * DD; t += 256) shw[t] = hw[t];
    for (int t = tid; t < DD * 3; t += 256) ssw[t] = sw[t];
    if (tid < DD) { sa[tid] = ab[tid]; sbp[tid] = ab[DD + tid]; shb[tid] = hb[tid]; }
    __syncthreads();

    int i = blockIdx.x * 256 + tid;
    float r[DD];
    const float4* hp = (const float4*)(h + (size_t)i * DD);
#pragma unroll
    for (int t = 0; t < DD / 4; ++t) {
        float4 v = hp[t];
        r[4 * t] = v.x; r[4 * t + 1] = v.y; r[4 * t + 2] = v.z; r[4 * t + 3] = v.w;
    }
#pragma unroll
    for (int c = 0; c < DD; ++c) r[c] = fmaf(sa[c], r[c], sbp[c]);
    float4* xp = (float4*)(xin + (size_t)i * DD);
#pragma unroll
    for (int t = 0; t < DD / 4; ++t)
        xp[t] = make_float4(r[4 * t], r[4 * t + 1], r[4 * t + 2], r[4 * t + 3]);

    float o[DD];
#pragma unroll
    for (int c = 0; c < DD; ++c) o[c] = shb[c];
#pragma unroll
    for (int k = 0; k < DD; ++k) {
        float v = r[k];
#pragma unroll
        for (int c = 0; c < DD; ++c) o[c] = fmaf(v, shw[k * DD + c], o[c]);
    }
    float4* hlp = (float4*)(hl + (size_t)i * DD);
#pragma unroll
    for (int t = 0; t < DD / 4; ++t)
        hlp[t] = make_float4(o[4 * t], o[4 * t + 1], o[4 * t + 2], o[4 * t + 3]);

    float s0 = 0.f, s1 = 0.f, s2 = 0.f;
#pragma unroll
    for (int k = 0; k < DD; ++k) {
        float v = r[k];
        s0 = fmaf(v, ssw[k * 3 + 0], s0);
        s1 = fmaf(v, ssw[k * 3 + 1], s1);
        s2 = fmaf(v, ssw[k * 3 + 2], s2);
    }
    sl4[i] = make_float4(s0, s1, s2, 0.f);
}

// ---------- K4: brute-force kNN — one wave per query, lane-sorted top-40 ----------
__global__ __launch_bounds__(256) void k_knn(const float4* __restrict__ sl4,
    int* __restrict__ idxo, float* __restrict__ esq,
    float* __restrict__ sumd, float* __restrict__ indeg)
{
    int lane = threadIdx.x & 63;
    int i = blockIdx.x * 4 + (threadIdx.x >> 6);   // query for this wave
    float4 q = sl4[i];

    float h_d = INFINITY;   // sorted ascending across lanes 0..39
    int   h_i = 0;
    float thr = INFINITY;   // current 40th-smallest (lane 39's h_d)

    for (int base = 0; base < NPTS; base += 64) {
        int j = base + lane;
        float4 p = sl4[j];
        float dx = q.x - p.x, dy = q.y - p.y, dz = q.z - p.z;
        float d2 = fmaf(dx, dx, fmaf(dy, dy, dz * dz));
        if (j == i) d2 = INFINITY;                 // self-exclusion
        unsigned long long m = __ballot(d2 < thr);
        while (m) {
            int src = __ffsll(m) - 1;
            m &= m - 1;
            float db = __shfl(d2, src);            // uniform broadcast
            if (db < thr) {                        // thr may have tightened
                int jb = base + src;
                unsigned long long pm = __ballot(db < h_d) & 0xFFFFFFFFFFull;
                int pos = __ffsll(pm) - 1;         // 0..39 guaranteed (db < thr)
                float sh = __shfl_up(h_d, 1);
                int   si = __shfl_up(h_i, 1);
                bool seg = (lane > pos) && (lane < KNN);
                h_d = (lane == pos) ? db : (seg ? sh : h_d);
                h_i = (lane == pos) ? jb : (seg ? si : h_i);
                thr = __shfl(h_d, KNN - 1);
            }
        }
    }

    if (lane < KNN) {
        int rb = i * KNN + lane;
        idxo[rb] = h_i;
        esq[rb] = h_d;
        float dist = sqrtf(h_d + 1e-6f);
        atomicAdd(&sumd[h_i], dist);
        atomicAdd(&indeg[h_i], 1.0f);
    }
}

// ---------- K5: both losses, flat over edges (+ first 8192 threads do loss1) ----------
__global__ __launch_bounds__(256) void k_loss(const float* __restrict__ esq,
    const int* __restrict__ idx, const float* __restrict__ sumd,
    const float* __restrict__ indeg, float* __restrict__ stats)
{
    int e = blockIdx.x * 256 + threadIdx.x;
    int j = idx[e];
    float dist = sqrtf(esq[e] + 1e-6f);
    float sd = sumd[j];
    float nrm = dist / (sd + 1e-4f);
    float dg = sd / (sd + 1e-4f) + 1e-4f;   // degs2[j] closed form
    float gn = dist / dg;
    float d = nrm - gn;
    float v2 = wave_sum(d * d);

    float t1 = 0.f;
    if (e < NPTS) {
        float id = indeg[e], sde = sumd[e];
        float av = id > 0.f ? sde / fmaxf(id, 1.f) : 0.f;
        float dd = av - 0.5f;
        t1 = dd * dd;
    }
    float v1 = wave_sum(t1);
    if ((threadIdx.x & 63) == 0) {
        atomicAdd(&stats[129], v2);
        if (v1 != 0.f) atomicAdd(&stats[128], v1);
    }
}

// ---------- K6: gather/aggregate + lin + post-MLP + BN2 stats ----------
// 16 threads per row (2 output channels each), 16 rows per 256-thread block.
#define RPB 16
__global__ __launch_bounds__(256) void k_agg(
    const int* __restrict__ idx, const float* __restrict__ esq,
    const float* __restrict__ hl, const float* __restrict__ xin,
    const float4* __restrict__ sl4,
    const float* __restrict__ lw, const float* __restrict__ lb,
    const float* __restrict__ pw1, const float* __restrict__ pb1,
    const float* __restrict__ pw2, const float* __restrict__ pb2,
    float* __restrict__ o, float* __restrict__ stats)
{
    __shared__ float slw[96 * DD], spw1[67 * DD], spw2[DD * DD];
    __shared__ float slb[DD], spb1[DD], spb2[DD];
    __shared__ float rin[RPB][100];  // [0,32)=mean [32,64)=max [64,96)=xin [96,99)=s_l
    __shared__ float rmid[RPB][73];  // [0,32)=xg  [36,68)=o1
    __shared__ float sstat[2 * DD];
    int tid = threadIdx.x;
    for (int t = tid; t < 96 * DD; t += 256) slw[t] = lw[t];
    for (int t = tid; t < 67 * DD; t += 256) spw1[t] = pw1[t];
    for (int t = tid; t < DD * DD; t += 256) spw2[t] = pw2[t];
    if (tid < DD) { slb[tid] = lb[tid]; spb1[tid] = pb1[tid]; spb2[tid] = pb2[tid]; }
    if (tid < 2 * DD) sstat[tid] = 0.f;
    __syncthreads();

    int r = tid >> 4, sub = tid & 15, cb = sub * 2;
    int g = blockIdx.x * RPB + r;

    // ---- gather (each thread: its 2 channels over all 40 neighbors) ----
    float sv0 = 0.f, sv1 = 0.f, mv0 = -INFINITY, mv1 = -INFINITY;
    int rb = g * KNN;
#pragma unroll 8
    for (int k = 0; k < KNN; ++k) {
        int j = idx[rb + k];
        float w = esq[rb + k];
        float2 hv = *(const float2*)(hl + (size_t)j * DD + cb);
        float m0 = hv.x * w, m1 = hv.y * w;
        sv0 += m0; sv1 += m1;
        mv0 = fmaxf(mv0, m0); mv1 = fmaxf(mv1, m1);
    }
    rin[r][cb] = sv0 * (1.f / KNN);
    rin[r][cb + 1] = sv1 * (1.f / KNN);
    rin[r][32 + cb] = mv0;
    rin[r][32 + cb + 1] = mv1;
    float2 xq = *(const float2*)(xin + (size_t)g * DD + cb);
    rin[r][64 + cb] = xq.x; rin[r][64 + cb + 1] = xq.y;
    if (sub == 0) { float4 s = sl4[g]; rin[r][96] = s.x; rin[r][97] = s.y; rin[r][98] = s.z; }
    __syncthreads();

    // ---- GEMM1: xg = [mean|max|xin] @ lin_w + lin_b ----
    float a0 = slb[cb], a1 = slb[cb + 1];
#pragma unroll
    for (int k = 0; k < 96; ++k) {
        float v = rin[r][k];
        a0 = fmaf(v, slw[k * DD + cb], a0);
        a1 = fmaf(v, slw[k * DD + cb + 1], a1);
    }
    rmid[r][cb] = a0; rmid[r][cb + 1] = a1;
    __syncthreads();

    // ---- GEMM2: o1 = elu([xg|s_l|xin] @ post_w1 + post_b1) ----
    a0 = spb1[cb]; a1 = spb1[cb + 1];
#pragma unroll
    for (int k = 0; k < DD; ++k) {
        float v = rmid[r][k];
        a0 = fmaf(v, spw1[k * DD + cb], a0);
        a1 = fmaf(v, spw1[k * DD + cb + 1], a1);
    }
#pragma unroll
    for (int s2 = 0; s2 < 3; ++s2) {
        float v = rin[r][96 + s2];
        a0 = fmaf(v, spw1[(32 + s2) * DD + cb], a0);
        a1 = fmaf(v, spw1[(32 + s2) * DD + cb + 1], a1);
    }
#pragma unroll
    for (int k = 0; k < DD; ++k) {
        float v = rin[r][64 + k];
        a0 = fmaf(v, spw1[(35 + k) * DD + cb], a0);
        a1 = fmaf(v, spw1[(35 + k) * DD + cb + 1], a1);
    }
    a0 = elu_f(a0); a1 = elu_f(a1);
    rmid[r][36 + cb] = a0; rmid[r][36 + cb + 1] = a1;
    __syncthreads();

    // ---- GEMM3: o2 = elu(o1 @ post_w2 + post_b2) ----
    a0 = spb2[cb]; a1 = spb2[cb + 1];
#pragma unroll
    for (int k = 0; k < DD; ++k) {
        float v = rmid[r][36 + k];
        a0 = fmaf(v, spw2[k * DD + cb], a0);
        a1 = fmaf(v, spw2[k * DD + cb + 1], a1);
    }
    a0 = elu_f(a0); a1 = elu_f(a1);
    *(float2*)(o + (size_t)g * DD + cb) = make_float2(a0, a1);

    // ---- BN2 stats: reduce the 4 rows within each wave, then LDS, then global ----
    float s0 = a0, s1 = a1, q0 = a0 * a0, q1 = a1 * a1;
#pragma unroll
    for (int m = 16; m < 64; m <<= 1) {
        s0 += __shfl_xor(s0, m); s1 += __shfl_xor(s1, m);
        q0 += __shfl_xor(q0, m); q1 += __shfl_xor(q1, m);
    }
    if ((tid & 48) == 0) {
        atomicAdd(&sstat[cb], s0); atomicAdd(&sstat[cb + 1], s1);
        atomicAdd(&sstat[DD + cb], q0); atomicAdd(&sstat[DD + cb + 1], q1);
    }
    __syncthreads();
    if (tid < DD) atomicAdd(&stats[64 + tid], sstat[tid]);
    else if (tid < 2 * DD) atomicAdd(&stats[96 + (tid - DD)], sstat[tid]);
}

// ---------- K7: finalize BN2 + write both losses ----------
__global__ void k_fin(const float* __restrict__ stats, const float* __restrict__ g,
                      const float* __restrict__ b, float* __restrict__ ab,
                      float* __restrict__ dout)
{
    int c = threadIdx.x;
    if (c < DD) {
        float mean = stats[64 + c] * (1.f / NPTS);
        float var = stats[96 + c] * (1.f / NPTS) - mean * mean;
        float a = g[c] * rsqrtf(var + 1e-5f);
        ab[64 + c] = a;
        ab[96 + c] = b[c] - a * mean;
    }
    if (c == 32) dout[NPTS * DD] = 0.01f * stats[128] * (1.f / NPTS);
    if (c == 33) dout[NPTS * DD + 1] = 0.1f * stats[129] * (1.f / ((float)NPTS * KNN));
}

// ---------- K8: out = a2*o + b2' ----------
__global__ __launch_bounds__(256) void k_out(const float* __restrict__ o,
    const float* __restrict__ ab, float* __restrict__ dout)
{
    int t = blockIdx.x * 256 + threadIdx.x;
    int c = t & (DD - 1);
    dout[t] = fmaf(ab[64 + c], o[t], ab[96 + c]);
}

extern "C" void kernel_launch(void* const* d_in, const int* in_sizes, int n_in,
                              void* d_out, int out_size, void* d_ws, size_t ws_size,
                              hipStream_t stream)
{
    (void)in_sizes; (void)n_in; (void)out_size; (void)ws_size;
    const float* x      = (const float*)d_in[0];
    const float* pre_w1 = (const float*)d_in[5];
    const float* pre_b1 = (const float*)d_in[6];
    const float* pre_w2 = (const float*)d_in[7];
    const float* pre_b2 = (const float*)d_in[8];
    const float* bn1_g  = (const float*)d_in[9];
    const float* bn1_b  = (const float*)d_in[10];
    const float* lin_s_w = (const float*)d_in[11];
    const float* lin_h_w = (const float*)d_in[12];
    const float* lin_h_b = (const float*)d_in[13];
    const float* lin_w   = (const float*)d_in[14];
    const float* lin_b   = (const float*)d_in[15];
    const float* post_w1 = (const float*)d_in[16];
    const float* post_b1 = (const float*)d_in[17];
    const float* post_w2 = (const float*)d_in[18];
    const float* post_b2 = (const float*)d_in[19];
    const float* bn2_g   = (const float*)d_in[20];
    const float* bn2_b   = (const float*)d_in[21];

    float* W = (float*)d_ws;
    float* h     = W + OFF_H;
    float* xin   = W + OFF_XIN;
    float* hl    = W + OFF_HL;
    float4* sl4  = (float4*)(W + OFF_SL);
    float* esq   = W + OFF_ESQ;
    float* o     = W + OFF_O;
    int*   idx   = (int*)(W + OFF_IDX);
    float* sumd  = W + OFF_SUMD;
    float* indeg = W + OFF_INDEG;
    float* stats = W + OFF_STATS;
    float* ab    = W + OFF_AB;
    float* dout  = (float*)d_out;

    hipMemsetAsync(W + OFF_SUMD, 0, ZERO_FLOATS * sizeof(float), stream);

    k_pre<<<NPTS / 256, 256, 0, stream>>>(x, pre_w1, pre_b1, pre_w2, pre_b2, h, stats);
    k_bn1_fin<<<1, 32, 0, stream>>>(stats, bn1_g, bn1_b, ab);
    k_proj<<<NPTS / 256, 256, 0, stream>>>(h, ab, lin_h_w, lin_h_b, lin_s_w, xin, hl, sl4);
    k_knn<<<NPTS / 4, 256, 0, stream>>>(sl4, idx, esq, sumd, indeg);
    k_loss<<<EDGES / 256, 256, 0, stream>>>(esq, idx, sumd, indeg, stats);
    k_agg<<<NPTS / RPB, 256, 0, stream>>>(idx, esq, hl, xin, sl4,
                                          lin_w, lin_b, post_w1, post_b1, post_w2, post_b2,
                                          o, stats);
    k_fin<<<1, 64, 0, stream>>>(stats, bn2_g, bn2_b, ab, dout);
    k_out<<<NPTS * DD / 256, 256, 0, stream>>>(o, ab, dout);
}

// Round 4
// 252.421 us; speedup vs baseline: 18.0823x; 1.2309x over previous
//
#include <hip/hip_runtime.h>
#include <math.h>

#define NPTS 8192
#define KNN 40
#define DD 32
#define CIN 16

// ---- ws layout (float offsets) ----
#define OFF_H      0u         // 8192*32
#define OFF_XIN    262144u    // 8192*32
#define OFF_HL     524288u    // 8192*32
#define OFF_SL     786432u    // 8192*4 (float4)
#define OFF_ESQ    819200u    // 8192*40
#define OFF_O      1146880u   // 8192*32
#define OFF_IDX    1409024u   // 8192*40 (int)
#define OFF_SUMD   1736704u   // 8192
#define OFF_INDEG  1744896u   // 8192
#define OFF_STATS  1753088u   // 136: bn1 s[32] ss[32], bn2 s[32] ss[32], loss1, loss2
#define ZERO_FLOATS (8192u + 8192u + 136u)

__device__ __forceinline__ float elu_f(float x) { return x > 0.f ? x : (expf(x) - 1.f); }

__device__ __forceinline__ float wave_sum(float v) {
#pragma unroll
    for (int m = 1; m < 64; m <<= 1) v += __shfl_xor(v, m);
    return v;
}

// ---------- K1: pre-MLP (elu(elu(x@W1+b1)@W2+b2)) + BN1 stats ----------
__global__ __launch_bounds__(64) void k_pre(const float* __restrict__ x,
    const float* __restrict__ w1, const float* __restrict__ b1,
    const float* __restrict__ w2, const float* __restrict__ b2,
    float* __restrict__ h, float* __restrict__ stats)
{
    __shared__ float sw1[CIN * DD], sw2[DD * DD], sb1[DD], sb2[DD];
    int tid = threadIdx.x;
    for (int t = tid; t < CIN * DD; t += 64) sw1[t] = w1[t];
    for (int t = tid; t < DD * DD; t += 64) sw2[t] = w2[t];
    if (tid < DD) { sb1[tid] = b1[tid]; sb2[tid] = b2[tid]; }
    __syncthreads();

    int i = blockIdx.x * 64 + tid;
    float xr[CIN];
    const float4* xp = (const float4*)(x + (size_t)i * CIN);
#pragma unroll
    for (int t = 0; t < CIN / 4; ++t) {
        float4 v = xp[t];
        xr[4 * t] = v.x; xr[4 * t + 1] = v.y; xr[4 * t + 2] = v.z; xr[4 * t + 3] = v.w;
    }
    float t1[DD];
#pragma unroll
    for (int c = 0; c < DD; ++c) t1[c] = sb1[c];
#pragma unroll
    for (int k = 0; k < CIN; ++k) {
        float xv = xr[k];
#pragma unroll
        for (int c = 0; c < DD; ++c) t1[c] = fmaf(xv, sw1[k * DD + c], t1[c]);
    }
#pragma unroll
    for (int c = 0; c < DD; ++c) t1[c] = elu_f(t1[c]);
    float t2[DD];
#pragma unroll
    for (int c = 0; c < DD; ++c) t2[c] = sb2[c];
#pragma unroll
    for (int k = 0; k < DD; ++k) {
        float xv = t1[k];
#pragma unroll
        for (int c = 0; c < DD; ++c) t2[c] = fmaf(xv, sw2[k * DD + c], t2[c]);
    }
#pragma unroll
    for (int c = 0; c < DD; ++c) t2[c] = elu_f(t2[c]);

    float4* hp = (float4*)(h + (size_t)i * DD);
#pragma unroll
    for (int t = 0; t < DD / 4; ++t)
        hp[t] = make_float4(t2[4 * t], t2[4 * t + 1], t2[4 * t + 2], t2[4 * t + 3]);

#pragma unroll
    for (int c = 0; c < DD; ++c) {
        float s = wave_sum(t2[c]);
        float q = wave_sum(t2[c] * t2[c]);
        if (tid == 0) { atomicAdd(&stats[c], s); atomicAdd(&stats[DD + c], q); }
    }
}

// ---------- K2: BN1(from stats) + h_l/s_l projections ----------
__global__ __launch_bounds__(64) void k_proj(const float* __restrict__ h,
    const float* __restrict__ stats,
    const float* __restrict__ g1, const float* __restrict__ b1g,
    const float* __restrict__ hw, const float* __restrict__ hb,
    const float* __restrict__ sw,
    float* __restrict__ xin, float* __restrict__ hl, float4* __restrict__ sl4)
{
    __shared__ float shw[DD * DD], ssw[DD * 3], sa[DD], sbp[DD], shb[DD];
    int tid = threadIdx.x;
    for (int t = tid; t < DD * DD; t += 64) shw[t] = hw[t];
    for (int t = tid; t < DD * 3; t += 64) ssw[t] = sw[t];
    if (tid < DD) {
        float mean = stats[tid] * (1.f / NPTS);
        float var = stats[DD + tid] * (1.f / NPTS) - mean * mean;
        float a = g1[tid] * rsqrtf(var + 1e-5f);
        sa[tid] = a;
        sbp[tid] = b1g[tid] - a * mean;
        shb[tid] = hb[tid];
    }
    __syncthreads();

    int i = blockIdx.x * 64 + tid;
    float r[DD];
    const float4* hp = (const float4*)(h + (size_t)i * DD);
#pragma unroll
    for (int t = 0; t < DD / 4; ++t) {
        float4 v = hp[t];
        r[4 * t] = v.x; r[4 * t + 1] = v.y; r[4 * t + 2] = v.z; r[4 * t + 3] = v.w;
    }
#pragma unroll
    for (int c = 0; c < DD; ++c) r[c] = fmaf(sa[c], r[c], sbp[c]);
    float4* xp = (float4*)(xin + (size_t)i * DD);
#pragma unroll
    for (int t = 0; t < DD / 4; ++t)
        xp[t] = make_float4(r[4 * t], r[4 * t + 1], r[4 * t + 2], r[4 * t + 3]);

    float o[DD];
#pragma unroll
    for (int c = 0; c < DD; ++c) o[c] = shb[c];
#pragma unroll
    for (int k = 0; k < DD; ++k) {
        float v = r[k];
#pragma unroll
        for (int c = 0; c < DD; ++c) o[c] = fmaf(v, shw[k * DD + c], o[c]);
    }
    float4* hlp = (float4*)(hl + (size_t)i * DD);
#pragma unroll
    for (int t = 0; t < DD / 4; ++t)
        hlp[t] = make_float4(o[4 * t], o[4 * t + 1], o[4 * t + 2], o[4 * t + 3]);

    float s0 = 0.f, s1 = 0.f, s2 = 0.f;
#pragma unroll
    for (int k = 0; k < DD; ++k) {
        float v = r[k];
        s0 = fmaf(v, ssw[k * 3 + 0], s0);
        s1 = fmaf(v, ssw[k * 3 + 1], s1);
        s2 = fmaf(v, ssw[k * 3 + 2], s2);
    }
    sl4[i] = make_float4(s0, s1, s2, 0.f);
}

// ---------- K3: kNN, two-pass threshold-estimated selection ----------
// Pass 1: per-lane top-2 values -> exact 40th of the 128-value pool (bit
// bisection) = guaranteed upper bound thr0 on the true 40th distance.
// Pass 2: insertion walk only for candidates <= thr0 (~45 inserts vs ~258).
__global__ __launch_bounds__(256) void k_knn(const float4* __restrict__ sl4,
    int* __restrict__ idxo, float* __restrict__ esq,
    float* __restrict__ sumd, float* __restrict__ indeg)
{
    int lane = threadIdx.x & 63;
    int i = blockIdx.x * 4 + (threadIdx.x >> 6);   // query for this wave
    float4 q = sl4[i];

    // ---- pass 1: per-lane smallest two distances ----
    float m0 = INFINITY, m1 = INFINITY;
    for (int base = 0; base < NPTS; base += 64) {
        int j = base + lane;
        float4 p = sl4[j];
        float dx = q.x - p.x, dy = q.y - p.y, dz = q.z - p.z;
        float d2 = fmaf(dx, dx, fmaf(dy, dy, dz * dz));
        if (j == i) d2 = INFINITY;
        float lo2 = fminf(d2, m0);
        float hi2 = fmaxf(d2, m0);
        m0 = lo2;
        m1 = fminf(m1, hi2);
    }

    // ---- exact 40th smallest of the 128 pooled values, via bit bisection ----
    unsigned bb0 = __float_as_uint(m0);
    unsigned bb1 = __float_as_uint(m1);
    unsigned blo = 0u, bhi = 0x7F800000u;          // d2 >= 0 -> bits monotone
    while (blo < bhi) {
        unsigned mid = (blo + bhi) >> 1;
        int cnt = __popcll(__ballot(bb0 <= mid)) + __popcll(__ballot(bb1 <= mid));
        if (cnt >= KNN) bhi = mid; else blo = mid + 1;
    }
    float thr0 = __uint_as_float(bhi);

    // ---- pass 2: exact top-40 among candidates <= thr0 ----
    float h_d = INFINITY;   // sorted ascending across lanes 0..39
    int   h_i = 0;
    float gate = thr0;      // min(thr0, current 40th of the list)

    for (int base = 0; base < NPTS; base += 64) {
        int j = base + lane;
        float4 p = sl4[j];
        float dx = q.x - p.x, dy = q.y - p.y, dz = q.z - p.z;
        float d2 = fmaf(dx, dx, fmaf(dy, dy, dz * dz));
        if (j == i) d2 = INFINITY;
        unsigned long long m = __ballot(d2 <= gate);
        while (m) {
            int src = __ffsll(m) - 1;
            m &= m - 1;
            float db = __shfl(d2, src);            // uniform broadcast
            if (db <= gate) {
                unsigned long long pm = __ballot(db < h_d) & 0xFFFFFFFFFFull;
                if (pm) {                          // pm==0 -> tie with 40th, skip
                    int jb = base + src;
                    int pos = __ffsll(pm) - 1;
                    float sh = __shfl_up(h_d, 1);
                    int   si = __shfl_up(h_i, 1);
                    bool seg = (lane > pos) && (lane < KNN);
                    h_d = (lane == pos) ? db : (seg ? sh : h_d);
                    h_i = (lane == pos) ? jb : (seg ? si : h_i);
                    gate = fminf(thr0, __shfl(h_d, KNN - 1));
                }
            }
        }
    }

    if (lane < KNN) {
        int rb = i * KNN + lane;
        idxo[rb] = h_i;
        esq[rb] = h_d;
        float dist = sqrtf(h_d + 1e-6f);
        atomicAdd(&sumd[h_i], dist);
        atomicAdd(&indeg[h_i], 1.0f);
    }
}

// ---------- K4: gather/aggregate + lin + post-MLP + BN2 stats + both losses ----------
// 16 threads per row (2 output channels each), 16 rows per 256-thread block.
#define RPB 16
__global__ __launch_bounds__(256) void k_agg(
    const int* __restrict__ idx, const float* __restrict__ esq,
    const float* __restrict__ hl, const float* __restrict__ xin,
    const float4* __restrict__ sl4,
    const float* __restrict__ sumd, const float* __restrict__ indeg,
    const float* __restrict__ lw, const float* __restrict__ lb,
    const float* __restrict__ pw1, const float* __restrict__ pb1,
    const float* __restrict__ pw2, const float* __restrict__ pb2,
    float* __restrict__ o, float* __restrict__ stats)
{
    __shared__ float slw[96 * DD], spw1[67 * DD], spw2[DD * DD];
    __shared__ float slb[DD], spb1[DD], spb2[DD];
    __shared__ float rin[RPB][100];  // [0,32)=mean [32,64)=max [64,96)=xin [96,99)=s_l
    __shared__ float rmid[RPB][73];  // [0,32)=xg  [36,68)=o1
    __shared__ float sstat[2 * DD];
    int tid = threadIdx.x;
    for (int t = tid; t < 96 * DD; t += 256) slw[t] = lw[t];
    for (int t = tid; t < 67 * DD; t += 256) spw1[t] = pw1[t];
    for (int t = tid; t < DD * DD; t += 256) spw2[t] = pw2[t];
    if (tid < DD) { slb[tid] = lb[tid]; spb1[tid] = pb1[tid]; spb2[tid] = pb2[tid]; }
    if (tid < 2 * DD) sstat[tid] = 0.f;
    __syncthreads();

    int r = tid >> 4, sub = tid & 15, cb = sub * 2;
    int g = blockIdx.x * RPB + r;

    // ---- gather + per-edge loss terms (edge k handled by sub == k%16) ----
    float sv0 = 0.f, sv1 = 0.f, mv0 = -INFINITY, mv1 = -INFINITY;
    float l2 = 0.f;
    int rb = g * KNN;
#pragma unroll
    for (int k = 0; k < KNN; ++k) {
        int j = idx[rb + k];
        float w = esq[rb + k];
        float2 hv = *(const float2*)(hl + (size_t)j * DD + cb);
        float m0 = hv.x * w, m1 = hv.y * w;
        sv0 += m0; sv1 += m1;
        mv0 = fmaxf(mv0, m0); mv1 = fmaxf(mv1, m1);
        if ((k & 15) == sub) {
            float dist = sqrtf(w + 1e-6f);
            float sd = sumd[j];
            float nrm = dist / (sd + 1e-4f);
            float dg = sd / (sd + 1e-4f) + 1e-4f;   // degs2[j] closed form
            float gn = dist / dg;
            float ddf = nrm - gn;
            l2 += ddf * ddf;
        }
    }
    float l1 = 0.f;
    if (sub == 0) {
        float id = indeg[g], sdg = sumd[g];
        float av = id > 0.f ? sdg / fmaxf(id, 1.f) : 0.f;
        float dd1 = av - 0.5f;
        l1 = dd1 * dd1;
    }
    float l2s = wave_sum(l2);
    float l1s = wave_sum(l1);
    if ((tid & 63) == 0) {
        atomicAdd(&stats[129], l2s);
        atomicAdd(&stats[128], l1s);
    }

    rin[r][cb] = sv0 * (1.f / KNN);
    rin[r][cb + 1] = sv1 * (1.f / KNN);
    rin[r][32 + cb] = mv0;
    rin[r][32 + cb + 1] = mv1;
    float2 xq = *(const float2*)(xin + (size_t)g * DD + cb);
    rin[r][64 + cb] = xq.x; rin[r][64 + cb + 1] = xq.y;
    if (sub == 0) { float4 s = sl4[g]; rin[r][96] = s.x; rin[r][97] = s.y; rin[r][98] = s.z; }
    __syncthreads();

    // ---- GEMM1: xg = [mean|max|xin] @ lin_w + lin_b ----
    float a0 = slb[cb], a1 = slb[cb + 1];
#pragma unroll
    for (int k = 0; k < 96; ++k) {
        float v = rin[r][k];
        a0 = fmaf(v, slw[k * DD + cb], a0);
        a1 = fmaf(v, slw[k * DD + cb + 1], a1);
    }
    rmid[r][cb] = a0; rmid[r][cb + 1] = a1;
    __syncthreads();

    // ---- GEMM2: o1 = elu([xg|s_l|xin] @ post_w1 + post_b1) ----
    a0 = spb1[cb]; a1 = spb1[cb + 1];
#pragma unroll
    for (int k = 0; k < DD; ++k) {
        float v = rmid[r][k];
        a0 = fmaf(v, spw1[k * DD + cb], a0);
        a1 = fmaf(v, spw1[k * DD + cb + 1], a1);
    }
#pragma unroll
    for (int s2 = 0; s2 < 3; ++s2) {
        float v = rin[r][96 + s2];
        a0 = fmaf(v, spw1[(32 + s2) * DD + cb], a0);
        a1 = fmaf(v, spw1[(32 + s2) * DD + cb + 1], a1);
    }
#pragma unroll
    for (int k = 0; k < DD; ++k) {
        float v = rin[r][64 + k];
        a0 = fmaf(v, spw1[(35 + k) * DD + cb], a0);
        a1 = fmaf(v, spw1[(35 + k) * DD + cb + 1], a1);
    }
    a0 = elu_f(a0); a1 = elu_f(a1);
    rmid[r][36 + cb] = a0; rmid[r][36 + cb + 1] = a1;
    __syncthreads();

    // ---- GEMM3: o2 = elu(o1 @ post_w2 + post_b2) ----
    a0 = spb2[cb]; a1 = spb2[cb + 1];
#pragma unroll
    for (int k = 0; k < DD; ++k) {
        float v = rmid[r][36 + k];
        a0 = fmaf(v, spw2[k * DD + cb], a0);
        a1 = fmaf(v, spw2[k * DD + cb + 1], a1);
    }
    a0 = elu_f(a0); a1 = elu_f(a1);
    *(float2*)(o + (size_t)g * DD + cb) = make_float2(a0, a1);

    // ---- BN2 stats: wave reduce (4 rows/wave) -> LDS -> global ----
    float s0 = a0, s1 = a1, q0 = a0 * a0, q1 = a1 * a1;
#pragma unroll
    for (int m = 16; m < 64; m <<= 1) {
        s0 += __shfl_xor(s0, m); s1 += __shfl_xor(s1, m);
        q0 += __shfl_xor(q0, m); q1 += __shfl_xor(q1, m);
    }
    if ((tid & 48) == 0) {
        atomicAdd(&sstat[cb], s0); atomicAdd(&sstat[cb + 1], s1);
        atomicAdd(&sstat[DD + cb], q0); atomicAdd(&sstat[DD + cb + 1], q1);
    }
    __syncthreads();
    if (tid < DD) atomicAdd(&stats[64 + tid], sstat[tid]);
    else if (tid < 2 * DD) atomicAdd(&stats[96 + (tid - DD)], sstat[tid]);
}

// ---------- K5: BN2 apply (float4) + loss writes ----------
__global__ __launch_bounds__(256) void k_out(const float* __restrict__ o,
    const float* __restrict__ stats, const float* __restrict__ g,
    const float* __restrict__ b, float* __restrict__ dout)
{
    __shared__ float sa[DD], sb[DD];
    int tid = threadIdx.x;
    if (tid < DD) {
        float mean = stats[64 + tid] * (1.f / NPTS);
        float var = stats[96 + tid] * (1.f / NPTS) - mean * mean;
        float a = g[tid] * rsqrtf(var + 1e-5f);
        sa[tid] = a;
        sb[tid] = b[tid] - a * mean;
    }
    __syncthreads();

    int t = blockIdx.x * 256 + tid;                 // float4 index over 65536
    float4 v = ((const float4*)o)[t];
    int cbase = (t * 4) & (DD - 1);
    float4 rr;
    rr.x = fmaf(sa[cbase + 0], v.x, sb[cbase + 0]);
    rr.y = fmaf(sa[cbase + 1], v.y, sb[cbase + 1]);
    rr.z = fmaf(sa[cbase + 2], v.z, sb[cbase + 2]);
    rr.w = fmaf(sa[cbase + 3], v.w, sb[cbase + 3]);
    ((float4*)dout)[t] = rr;

    if (blockIdx.x == 0) {
        if (tid == DD)     dout[NPTS * DD]     = 0.01f * stats[128] * (1.f / NPTS);
        if (tid == DD + 1) dout[NPTS * DD + 1] = 0.1f  * stats[129] * (1.f / ((float)NPTS * KNN));
    }
}

extern "C" void kernel_launch(void* const* d_in, const int* in_sizes, int n_in,
                              void* d_out, int out_size, void* d_ws, size_t ws_size,
                              hipStream_t stream)
{
    (void)in_sizes; (void)n_in; (void)out_size; (void)ws_size;
    const float* x      = (const float*)d_in[0];
    const float* pre_w1 = (const float*)d_in[5];
    const float* pre_b1 = (const float*)d_in[6];
    const float* pre_w2 = (const float*)d_in[7];
    const float* pre_b2 = (const float*)d_in[8];
    const float* bn1_g  = (const float*)d_in[9];
    const float* bn1_b  = (const float*)d_in[10];
    const float* lin_s_w = (const float*)d_in[11];
    const float* lin_h_w = (const float*)d_in[12];
    const float* lin_h_b = (const float*)d_in[13];
    const float* lin_w   = (const float*)d_in[14];
    const float* lin_b   = (const float*)d_in[15];
    const float* post_w1 = (const float*)d_in[16];
    const float* post_b1 = (const float*)d_in[17];
    const float* post_w2 = (const float*)d_in[18];
    const float* post_b2 = (const float*)d_in[19];
    const float* bn2_g   = (const float*)d_in[20];
    const float* bn2_b   = (const float*)d_in[21];

    float* W = (float*)d_ws;
    float* h     = W + OFF_H;
    float* xin   = W + OFF_XIN;
    float* hl    = W + OFF_HL;
    float4* sl4  = (float4*)(W + OFF_SL);
    float* esq   = W + OFF_ESQ;
    float* o     = W + OFF_O;
    int*   idx   = (int*)(W + OFF_IDX);
    float* sumd  = W + OFF_SUMD;
    float* indeg = W + OFF_INDEG;
    float* stats = W + OFF_STATS;
    float* dout  = (float*)d_out;

    hipMemsetAsync(W + OFF_SUMD, 0, ZERO_FLOATS * sizeof(float), stream);

    k_pre<<<NPTS / 64, 64, 0, stream>>>(x, pre_w1, pre_b1, pre_w2, pre_b2, h, stats);
    k_proj<<<NPTS / 64, 64, 0, stream>>>(h, stats, bn1_g, bn1_b,
                                         lin_h_w, lin_h_b, lin_s_w, xin, hl, sl4);
    k_knn<<<NPTS / 4, 256, 0, stream>>>(sl4, idx, esq, sumd, indeg);
    k_agg<<<NPTS / RPB, 256, 0, stream>>>(idx, esq, hl, xin, sl4, sumd, indeg,
                                          lin_w, lin_b, post_w1, post_b1, post_w2, post_b2,
                                          o, stats);
    k_out<<<NPTS * DD / 1024, 256, 0, stream>>>(o, stats, bn2_g, bn2_b, dout);
}

// Round 5
// 187.828 us; speedup vs baseline: 24.3007x; 1.3439x over previous
//
#include <hip/hip_runtime.h>
#include <math.h>

#define NPTS 8192
#define KNN 40
#define DD 32
#define CIN 16
#define ROWS 16      // rows per 256-thread block in row-split kernels
#define CAP 96       // kNN candidate buffer per query

// ---- ws layout (float offsets) ----
#define OFF_H      0u         // 8192*32
#define OFF_XIN    262144u    // 8192*32
#define OFF_HL     524288u    // 8192*32
#define OFF_SL     786432u    // 8192*4 (float4: s0,s1,s2, 0.5*|s|^2)
#define OFF_ESQ    819200u    // 8192*40
#define OFF_O      1146880u   // 8192*32
#define OFF_IDX    1409024u   // 8192*40 (int)
#define OFF_SUMD   1736704u   // 8192
#define OFF_INDEG  1744896u   // 8192
#define OFF_STATS  1753088u   // 136: bn1 s[32] ss[32], bn2 s[32] ss[32], loss1, loss2
#define ZERO_FLOATS (8192u + 8192u + 136u)

__device__ __forceinline__ float elu_f(float x) { return x > 0.f ? x : (expf(x) - 1.f); }

__device__ __forceinline__ float wave_sum(float v) {
#pragma unroll
    for (int m = 1; m < 64; m <<= 1) v += __shfl_xor(v, m);
    return v;
}

// order-preserving float->uint key (handles negative e values)
__device__ __forceinline__ unsigned fkey(float x) {
    unsigned b = __float_as_uint(x);
    return b ^ ((unsigned)((int)b >> 31) | 0x80000000u);
}
__device__ __forceinline__ float kinv(unsigned k) {
    unsigned b = (k & 0x80000000u) ? (k ^ 0x80000000u) : ~k;
    return __uint_as_float(b);
}

// kth-smallest (1-based) of the 128 values {u0,u1} x 64 lanes, exact, wave-uniform
__device__ __forceinline__ unsigned bisect_kth(unsigned u0, unsigned u1, int kth) {
    unsigned lo = 0u, hi = 0xFFFFFFFFu;
    while (lo < hi) {
        unsigned mid = lo + ((hi - lo) >> 1);
        int cnt = __popcll(__ballot(u0 <= mid)) + __popcll(__ballot(u1 <= mid));
        if (cnt >= kth) hi = mid; else lo = mid + 1;
    }
    return hi;
}

// ---------- K1: pre-MLP + BN1 stats (16 thr/row, 2 ch/thr) ----------
__global__ __launch_bounds__(256) void k_pre(const float* __restrict__ x,
    const float* __restrict__ w1, const float* __restrict__ b1,
    const float* __restrict__ w2, const float* __restrict__ b2,
    float* __restrict__ h, float* __restrict__ stats)
{
    __shared__ float sw1[CIN * DD], sw2[DD * DD], sb1[DD], sb2[DD];
    __shared__ float rt1[ROWS][DD + 4];
    __shared__ float sstat[2 * DD];
    int tid = threadIdx.x;
    for (int t = tid; t < CIN * DD; t += 256) sw1[t] = w1[t];
    for (int t = tid; t < DD * DD; t += 256) sw2[t] = w2[t];
    if (tid < DD) { sb1[tid] = b1[tid]; sb2[tid] = b2[tid]; }
    if (tid < 2 * DD) sstat[tid] = 0.f;
    __syncthreads();

    int r = tid >> 4, sub = tid & 15, cb = sub * 2;
    int g = blockIdx.x * ROWS + r;

    const float4* xp = (const float4*)(x + (size_t)g * CIN);
    float xr[CIN];
#pragma unroll
    for (int t = 0; t < CIN / 4; ++t) {
        float4 v = xp[t];
        xr[4 * t] = v.x; xr[4 * t + 1] = v.y; xr[4 * t + 2] = v.z; xr[4 * t + 3] = v.w;
    }
    float a0 = sb1[cb], a1 = sb1[cb + 1];
#pragma unroll
    for (int k = 0; k < CIN; ++k) {
        float2 w = *(const float2*)&sw1[k * DD + cb];
        a0 = fmaf(xr[k], w.x, a0);
        a1 = fmaf(xr[k], w.y, a1);
    }
    a0 = elu_f(a0); a1 = elu_f(a1);
    rt1[r][cb] = a0; rt1[r][cb + 1] = a1;
    __syncthreads();

    float o0 = sb2[cb], o1 = sb2[cb + 1];
#pragma unroll
    for (int k = 0; k < DD; ++k) {
        float v = rt1[r][k];
        float2 w = *(const float2*)&sw2[k * DD + cb];
        o0 = fmaf(v, w.x, o0);
        o1 = fmaf(v, w.y, o1);
    }
    o0 = elu_f(o0); o1 = elu_f(o1);
    *(float2*)(h + (size_t)g * DD + cb) = make_float2(o0, o1);

    // BN1 stats: reduce the 4 rows in this wave, then LDS, then global
    float s0 = o0, s1 = o1, q0 = o0 * o0, q1 = o1 * o1;
#pragma unroll
    for (int m = 16; m < 64; m <<= 1) {
        s0 += __shfl_xor(s0, m); s1 += __shfl_xor(s1, m);
        q0 += __shfl_xor(q0, m); q1 += __shfl_xor(q1, m);
    }
    if ((tid & 48) == 0) {
        atomicAdd(&sstat[cb], s0); atomicAdd(&sstat[cb + 1], s1);
        atomicAdd(&sstat[DD + cb], q0); atomicAdd(&sstat[DD + cb + 1], q1);
    }
    __syncthreads();
    if (tid < 2 * DD) atomicAdd(&stats[tid], sstat[tid]);
}

// ---------- K2: BN1 apply + h_l/s_l projections (16 thr/row) ----------
__global__ __launch_bounds__(256) void k_proj(const float* __restrict__ h,
    const float* __restrict__ stats,
    const float* __restrict__ g1, const float* __restrict__ b1g,
    const float* __restrict__ hw, const float* __restrict__ hb,
    const float* __restrict__ sw,
    float* __restrict__ xin, float* __restrict__ hl, float4* __restrict__ sl4)
{
    __shared__ float shw[DD * DD], ssw[DD * 3], sa[DD], sbp[DD], shb[DD];
    __shared__ float rr[ROWS][DD + 4];   // [0,32)=BN'd row, [32,35)=s_l
    int tid = threadIdx.x;
    for (int t = tid; t < DD * DD; t += 256) shw[t] = hw[t];
    if (tid < DD * 3) ssw[tid] = sw[tid];
    if (tid < DD) {
        float mean = stats[tid] * (1.f / NPTS);
        float var = stats[DD + tid] * (1.f / NPTS) - mean * mean;
        float a = g1[tid] * rsqrtf(var + 1e-5f);
        sa[tid] = a;
        sbp[tid] = b1g[tid] - a * mean;
        shb[tid] = hb[tid];
    }
    __syncthreads();

    int r = tid >> 4, sub = tid & 15, cb = sub * 2;
    int g = blockIdx.x * ROWS + r;

    float2 hv = *(const float2*)(h + (size_t)g * DD + cb);
    float v0 = fmaf(sa[cb], hv.x, sbp[cb]);
    float v1 = fmaf(sa[cb + 1], hv.y, sbp[cb + 1]);
    rr[r][cb] = v0; rr[r][cb + 1] = v1;
    *(float2*)(xin + (size_t)g * DD + cb) = make_float2(v0, v1);
    __syncthreads();

    float o0 = shb[cb], o1 = shb[cb + 1];
#pragma unroll
    for (int k = 0; k < DD; ++k) {
        float v = rr[r][k];
        float2 w = *(const float2*)&shw[k * DD + cb];
        o0 = fmaf(v, w.x, o0);
        o1 = fmaf(v, w.y, o1);
    }
    *(float2*)(hl + (size_t)g * DD + cb) = make_float2(o0, o1);

    if (sub < 3) {
        float s = 0.f;
#pragma unroll
        for (int k = 0; k < DD; ++k) s = fmaf(rr[r][k], ssw[k * 3 + sub], s);
        rr[r][DD + sub] = s;
    }
    __syncthreads();
    if (sub == 0) {
        float s0 = rr[r][DD], s1 = rr[r][DD + 1], s2 = rr[r][DD + 2];
        sl4[g] = make_float4(s0, s1, s2, 0.5f * (s0 * s0 + s1 * s1 + s2 * s2));
    }
}

// ---------- K3: kNN — 2 queries/wave, e-form distances, collect-then-select ----
// e(j) = 0.5|p_j|^2 - q.p_j  (monotone in d2 for fixed q; d2 = 2*(e + 0.5|q|^2)).
// Pass 1: per-lane top-2 of e -> exact 41st of the 128-value pool (self stays
// in-stream; 41st of any subset >= 41st of full = 40th excluding self).
// Pass 2: append all e <= thr0 to LDS buffer via ballot-prefix (~45 hits).
// Select: exact 40th via bit-bisection, emit exactly 40 (ties rank-filled).
__device__ __forceinline__ void select_emit(const float2* bufq, int C, int qidx,
    float qw, int lane, int* __restrict__ idxo, float* __restrict__ esq,
    float* __restrict__ sumd, float* __restrict__ indeg)
{
    float e0 = INFINITY, e1 = INFINITY;
    int j0 = -1, j1 = -1;
    if (lane < C) { float2 t = bufq[lane]; e0 = t.x; j0 = __float_as_int(t.y); }
    if (lane + 64 < C) { float2 t = bufq[lane + 64]; e1 = t.x; j1 = __float_as_int(t.y); }
    if (j0 == qidx) e0 = INFINITY;   // drop self
    if (j1 == qidx) e1 = INFINITY;
    unsigned u0 = fkey(e0), u1 = fkey(e1);
    unsigned thr = bisect_kth(u0, u1, KNN);
    unsigned long long ltm = (1ull << lane) - 1;
    unsigned long long mlt0 = __ballot(u0 < thr), mlt1 = __ballot(u1 < thr);
    unsigned long long meq0 = __ballot(u0 == thr), meq1 = __ballot(u1 == thr);
    int nlt = __popcll(mlt0) + __popcll(mlt1);
    int need = KNN - nlt;
    int rb = qidx * KNN;

    int pos = -1;
    if (u0 < thr) pos = __popcll(mlt0 & ltm);
    else if (u0 == thr) { int rk = __popcll(meq0 & ltm); if (rk < need) pos = nlt + rk; }
    if (pos >= 0) {
        float d2 = fmaxf(2.f * (e0 + qw), 0.f);
        idxo[rb + pos] = j0; esq[rb + pos] = d2;
        float dist = sqrtf(d2 + 1e-6f);
        atomicAdd(&sumd[j0], dist); atomicAdd(&indeg[j0], 1.f);
    }
    pos = -1;
    if (u1 < thr) pos = __popcll(mlt0) + __popcll(mlt1 & ltm);
    else if (u1 == thr) {
        int rk = __popcll(meq0) + __popcll(meq1 & ltm);
        if (rk < need) pos = nlt + rk;
    }
    if (pos >= 0) {
        float d2 = fmaxf(2.f * (e1 + qw), 0.f);
        idxo[rb + pos] = j1; esq[rb + pos] = d2;
        float dist = sqrtf(d2 + 1e-6f);
        atomicAdd(&sumd[j1], dist); atomicAdd(&indeg[j1], 1.f);
    }
}

__global__ __launch_bounds__(256) void k_knn(const float4* __restrict__ sl4,
    int* __restrict__ idxo, float* __restrict__ esq,
    float* __restrict__ sumd, float* __restrict__ indeg)
{
    __shared__ float2 buf[8][CAP];
    int tid = threadIdx.x, lane = tid & 63, wid = tid >> 6;
    int qai = blockIdx.x * 8 + wid * 2;
    int qbi = qai + 1;
    float4 qa = sl4[qai], qb = sl4[qbi];

    // ---- pass 1: per-lane top-2 of e for each query ----
    float m0a = INFINITY, m1a = INFINITY, m0b = INFINITY, m1b = INFINITY;
    for (int base = 0; base < NPTS; base += 64) {
        float4 p = sl4[base + lane];
        float ea = fmaf(-qa.x, p.x, fmaf(-qa.y, p.y, fmaf(-qa.z, p.z, p.w)));
        float eb = fmaf(-qb.x, p.x, fmaf(-qb.y, p.y, fmaf(-qb.z, p.z, p.w)));
        float lo = fminf(ea, m0a), hi = fmaxf(ea, m0a);
        m0a = lo; m1a = fminf(m1a, hi);
        lo = fminf(eb, m0b); hi = fmaxf(eb, m0b);
        m0b = lo; m1b = fminf(m1b, hi);
    }
    float thrfa = kinv(bisect_kth(fkey(m0a), fkey(m1a), KNN + 1));
    float thrfb = kinv(bisect_kth(fkey(m0b), fkey(m1b), KNN + 1));

    // ---- pass 2: collect candidates ----
    unsigned long long ltm = (1ull << lane) - 1;
    int ca = 0, cbn = 0;
    float2* bufa = buf[wid * 2];
    float2* bufb = buf[wid * 2 + 1];
    for (int base = 0; base < NPTS; base += 64) {
        float4 p = sl4[base + lane];
        int jj = base + lane;
        float ea = fmaf(-qa.x, p.x, fmaf(-qa.y, p.y, fmaf(-qa.z, p.z, p.w)));
        float eb = fmaf(-qb.x, p.x, fmaf(-qb.y, p.y, fmaf(-qb.z, p.z, p.w)));
        unsigned long long ma = __ballot(ea <= thrfa);
        unsigned long long mb = __ballot(eb <= thrfb);
        if (ma) {
            if (ea <= thrfa) {
                int pos = ca + __popcll(ma & ltm);
                if (pos < CAP) bufa[pos] = make_float2(ea, __int_as_float(jj));
            }
            ca += __popcll(ma);
        }
        if (mb) {
            if (eb <= thrfb) {
                int pos = cbn + __popcll(mb & ltm);
                if (pos < CAP) bufb[pos] = make_float2(eb, __int_as_float(jj));
            }
            cbn += __popcll(mb);
        }
    }
    __syncthreads();

    select_emit(bufa, ca < CAP ? ca : CAP, qai, qa.w, lane, idxo, esq, sumd, indeg);
    select_emit(bufb, cbn < CAP ? cbn : CAP, qbi, qb.w, lane, idxo, esq, sumd, indeg);
}

// ---------- K4: gather/aggregate + lin + post-MLP + BN2 stats + both losses ----------
__global__ __launch_bounds__(256) void k_agg(
    const int* __restrict__ idx, const float* __restrict__ esq,
    const float* __restrict__ hl, const float* __restrict__ xin,
    const float4* __restrict__ sl4,
    const float* __restrict__ sumd, const float* __restrict__ indeg,
    const float* __restrict__ lw, const float* __restrict__ lb,
    const float* __restrict__ pw1, const float* __restrict__ pb1,
    const float* __restrict__ pw2, const float* __restrict__ pb2,
    float* __restrict__ o, float* __restrict__ stats)
{
    __shared__ float slw[96 * DD], spw1[67 * DD], spw2[DD * DD];
    __shared__ float slb[DD], spb1[DD], spb2[DD];
    __shared__ float rin[ROWS][100];  // [0,32)=mean [32,64)=max [64,96)=xin [96,99)=s_l
    __shared__ float rmid[ROWS][73];  // [0,32)=xg  [36,68)=o1
    __shared__ float sstat[2 * DD];
    int tid = threadIdx.x;
    for (int t = tid; t < 96 * DD; t += 256) slw[t] = lw[t];
    for (int t = tid; t < 67 * DD; t += 256) spw1[t] = pw1[t];
    for (int t = tid; t < DD * DD; t += 256) spw2[t] = pw2[t];
    if (tid < DD) { slb[tid] = lb[tid]; spb1[tid] = pb1[tid]; spb2[tid] = pb2[tid]; }
    if (tid < 2 * DD) sstat[tid] = 0.f;
    __syncthreads();

    int r = tid >> 4, sub = tid & 15, cb = sub * 2;
    int g = blockIdx.x * ROWS + r;

    float sv0 = 0.f, sv1 = 0.f, mv0 = -INFINITY, mv1 = -INFINITY;
    float l2 = 0.f;
    int rb = g * KNN;
#pragma unroll
    for (int k = 0; k < KNN; ++k) {
        int j = idx[rb + k];
        float w = esq[rb + k];
        float2 hv = *(const float2*)(hl + (size_t)j * DD + cb);
        float m0 = hv.x * w, m1 = hv.y * w;
        sv0 += m0; sv1 += m1;
        mv0 = fmaxf(mv0, m0); mv1 = fmaxf(mv1, m1);
        if ((k & 15) == sub) {
            float dist = sqrtf(w + 1e-6f);
            float sd = sumd[j];
            float nrm = dist / (sd + 1e-4f);
            float dg = sd / (sd + 1e-4f) + 1e-4f;   // degs2[j] closed form
            float gn = dist / dg;
            float ddf = nrm - gn;
            l2 += ddf * ddf;
        }
    }
    float l1 = 0.f;
    if (sub == 0) {
        float id = indeg[g], sdg = sumd[g];
        float av = id > 0.f ? sdg / fmaxf(id, 1.f) : 0.f;
        float dd1 = av - 0.5f;
        l1 = dd1 * dd1;
    }
    float l2s = wave_sum(l2);
    float l1s = wave_sum(l1);
    if ((tid & 63) == 0) {
        atomicAdd(&stats[129], l2s);
        atomicAdd(&stats[128], l1s);
    }

    rin[r][cb] = sv0 * (1.f / KNN);
    rin[r][cb + 1] = sv1 * (1.f / KNN);
    rin[r][32 + cb] = mv0;
    rin[r][32 + cb + 1] = mv1;
    float2 xq = *(const float2*)(xin + (size_t)g * DD + cb);
    rin[r][64 + cb] = xq.x; rin[r][64 + cb + 1] = xq.y;
    if (sub == 0) { float4 s = sl4[g]; rin[r][96] = s.x; rin[r][97] = s.y; rin[r][98] = s.z; }
    __syncthreads();

    float a0 = slb[cb], a1 = slb[cb + 1];
#pragma unroll
    for (int k = 0; k < 96; ++k) {
        float v = rin[r][k];
        a0 = fmaf(v, slw[k * DD + cb], a0);
        a1 = fmaf(v, slw[k * DD + cb + 1], a1);
    }
    rmid[r][cb] = a0; rmid[r][cb + 1] = a1;
    __syncthreads();

    a0 = spb1[cb]; a1 = spb1[cb + 1];
#pragma unroll
    for (int k = 0; k < DD; ++k) {
        float v = rmid[r][k];
        a0 = fmaf(v, spw1[k * DD + cb], a0);
        a1 = fmaf(v, spw1[k * DD + cb + 1], a1);
    }
#pragma unroll
    for (int s2 = 0; s2 < 3; ++s2) {
        float v = rin[r][96 + s2];
        a0 = fmaf(v, spw1[(32 + s2) * DD + cb], a0);
        a1 = fmaf(v, spw1[(32 + s2) * DD + cb + 1], a1);
    }
#pragma unroll
    for (int k = 0; k < DD; ++k) {
        float v = rin[r][64 + k];
        a0 = fmaf(v, spw1[(35 + k) * DD + cb], a0);
        a1 = fmaf(v, spw1[(35 + k) * DD + cb + 1], a1);
    }
    a0 = elu_f(a0); a1 = elu_f(a1);
    rmid[r][36 + cb] = a0; rmid[r][36 + cb + 1] = a1;
    __syncthreads();

    a0 = spb2[cb]; a1 = spb2[cb + 1];
#pragma unroll
    for (int k = 0; k < DD; ++k) {
        float v = rmid[r][36 + k];
        a0 = fmaf(v, spw2[k * DD + cb], a0);
        a1 = fmaf(v, spw2[k * DD + cb + 1], a1);
    }
    a0 = elu_f(a0); a1 = elu_f(a1);
    *(float2*)(o + (size_t)g * DD + cb) = make_float2(a0, a1);

    float s0 = a0, s1 = a1, q0 = a0 * a0, q1 = a1 * a1;
#pragma unroll
    for (int m = 16; m < 64; m <<= 1) {
        s0 += __shfl_xor(s0, m); s1 += __shfl_xor(s1, m);
        q0 += __shfl_xor(q0, m); q1 += __shfl_xor(q1, m);
    }
    if ((tid & 48) == 0) {
        atomicAdd(&sstat[cb], s0); atomicAdd(&sstat[cb + 1], s1);
        atomicAdd(&sstat[DD + cb], q0); atomicAdd(&sstat[DD + cb + 1], q1);
    }
    __syncthreads();
    if (tid < DD) atomicAdd(&stats[64 + tid], sstat[tid]);
    else if (tid < 2 * DD) atomicAdd(&stats[96 + (tid - DD)], sstat[tid]);
}

// ---------- K5: BN2 apply (float4) + loss writes ----------
__global__ __launch_bounds__(256) void k_out(const float* __restrict__ o,
    const float* __restrict__ stats, const float* __restrict__ g,
    const float* __restrict__ b, float* __restrict__ dout)
{
    __shared__ float sa[DD], sb[DD];
    int tid = threadIdx.x;
    if (tid < DD) {
        float mean = stats[64 + tid] * (1.f / NPTS);
        float var = stats[96 + tid] * (1.f / NPTS) - mean * mean;
        float a = g[tid] * rsqrtf(var + 1e-5f);
        sa[tid] = a;
        sb[tid] = b[tid] - a * mean;
    }
    __syncthreads();

    int t = blockIdx.x * 256 + tid;                 // float4 index over 65536
    float4 v = ((const float4*)o)[t];
    int cbase = (t * 4) & (DD - 1);
    float4 rr;
    rr.x = fmaf(sa[cbase + 0], v.x, sb[cbase + 0]);
    rr.y = fmaf(sa[cbase + 1], v.y, sb[cbase + 1]);
    rr.z = fmaf(sa[cbase + 2], v.z, sb[cbase + 2]);
    rr.w = fmaf(sa[cbase + 3], v.w, sb[cbase + 3]);
    ((float4*)dout)[t] = rr;

    if (blockIdx.x == 0) {
        if (tid == DD)     dout[NPTS * DD]     = 0.01f * stats[128] * (1.f / NPTS);
        if (tid == DD + 1) dout[NPTS * DD + 1] = 0.1f  * stats[129] * (1.f / ((float)NPTS * KNN));
    }
}

extern "C" void kernel_launch(void* const* d_in, const int* in_sizes, int n_in,
                              void* d_out, int out_size, void* d_ws, size_t ws_size,
                              hipStream_t stream)
{
    (void)in_sizes; (void)n_in; (void)out_size; (void)ws_size;
    const float* x      = (const float*)d_in[0];
    const float* pre_w1 = (const float*)d_in[5];
    const float* pre_b1 = (const float*)d_in[6];
    const float* pre_w2 = (const float*)d_in[7];
    const float* pre_b2 = (const float*)d_in[8];
    const float* bn1_g  = (const float*)d_in[9];
    const float* bn1_b  = (const float*)d_in[10];
    const float* lin_s_w = (const float*)d_in[11];
    const float* lin_h_w = (const float*)d_in[12];
    const float* lin_h_b = (const float*)d_in[13];
    const float* lin_w   = (const float*)d_in[14];
    const float* lin_b   = (const float*)d_in[15];
    const float* post_w1 = (const float*)d_in[16];
    const float* post_b1 = (const float*)d_in[17];
    const float* post_w2 = (const float*)d_in[18];
    const float* post_b2 = (const float*)d_in[19];
    const float* bn2_g   = (const float*)d_in[20];
    const float* bn2_b   = (const float*)d_in[21];

    float* W = (float*)d_ws;
    float* h     = W + OFF_H;
    float* xin   = W + OFF_XIN;
    float* hl    = W + OFF_HL;
    float4* sl4  = (float4*)(W + OFF_SL);
    float* esq   = W + OFF_ESQ;
    float* o     = W + OFF_O;
    int*   idx   = (int*)(W + OFF_IDX);
    float* sumd  = W + OFF_SUMD;
    float* indeg = W + OFF_INDEG;
    float* stats = W + OFF_STATS;
    float* dout  = (float*)d_out;

    hipMemsetAsync(W + OFF_SUMD, 0, ZERO_FLOATS * sizeof(float), stream);

    k_pre<<<NPTS / ROWS, 256, 0, stream>>>(x, pre_w1, pre_b1, pre_w2, pre_b2, h, stats);
    k_proj<<<NPTS / ROWS, 256, 0, stream>>>(h, stats, bn1_g, bn1_b,
                                            lin_h_w, lin_h_b, lin_s_w, xin, hl, sl4);
    k_knn<<<NPTS / 8, 256, 0, stream>>>(sl4, idx, esq, sumd, indeg);
    k_agg<<<NPTS / ROWS, 256, 0, stream>>>(idx, esq, hl, xin, sl4, sumd, indeg,
                                           lin_w, lin_b, post_w1, post_b1, post_w2, post_b2,
                                           o, stats);
    k_out<<<NPTS * DD / 1024, 256, 0, stream>>>(o, stats, bn2_g, bn2_b, dout);
}

// Round 6
// 131.902 us; speedup vs baseline: 34.6041x; 1.4240x over previous
//
#include <hip/hip_runtime.h>
#include <math.h>

#define NPTS 8192
#define KNN 40
#define DD 32
#define CIN 16
#define RPB 8        // rows per block (32 threads per row)
#define CAP 96       // kNN candidate buffer per query

// ---- ws layout (float offsets) ----
#define OFF_H      0u         // 8192*32
#define OFF_XIN    262144u    // 8192*32
#define OFF_HL     524288u    // 8192*32
#define OFF_SL     786432u    // 8192*4 (float4: s0,s1,s2, 0.5*|s|^2)
#define OFF_ESQ    819200u    // 8192*40
#define OFF_O      1146880u   // 8192*32
#define OFF_IDX    1409024u   // 8192*40 (int)
#define OFF_SUMD   1736704u   // 8192
#define OFF_INDEG  1744896u   // 8192
#define OFF_STATS  1753088u   // 130 slots x 32-float stride (1 line/slot)
#define ZERO_FLOATS (8192u + 8192u + 130u * 32u)

// slot map: 0..31 bn1 sum, 32..63 bn1 sq, 64..95 bn2 sum, 96..127 bn2 sq,
//           128 loss1, 129 loss2
#define ST(i) stats[(i) * 32]

__device__ __forceinline__ float elu_f(float x) { return x > 0.f ? x : (expf(x) - 1.f); }

__device__ __forceinline__ float grp_sum32(float v) {
#pragma unroll
    for (int m = 1; m < 32; m <<= 1) v += __shfl_xor(v, m);
    return v;
}

// order-preserving float->uint key
__device__ __forceinline__ unsigned fkey(float x) {
    unsigned b = __float_as_uint(x);
    return b ^ ((unsigned)((int)b >> 31) | 0x80000000u);
}
__device__ __forceinline__ float kinv(unsigned k) {
    unsigned b = (k & 0x80000000u) ? (k ^ 0x80000000u) : ~k;
    return __uint_as_float(b);
}

// kth-smallest (1-based) of the 128 values {u0,u1} x 64 lanes, exact
__device__ __forceinline__ unsigned bisect_kth(unsigned u0, unsigned u1, int kth) {
    unsigned lo = 0u, hi = 0xFFFFFFFFu;
    while (lo < hi) {
        unsigned mid = lo + ((hi - lo) >> 1);
        int cnt = __popcll(__ballot(u0 <= mid)) + __popcll(__ballot(u1 <= mid));
        if (cnt >= kth) hi = mid; else lo = mid + 1;
    }
    return hi;
}

// ---------- K1: pre-MLP + BN1 stats (32 thr/row, 1 ch/thr) ----------
__global__ __launch_bounds__(256) void k_pre(const float* __restrict__ x,
    const float* __restrict__ w1, const float* __restrict__ b1,
    const float* __restrict__ w2, const float* __restrict__ b2,
    float* __restrict__ h, float* __restrict__ stats)
{
    __shared__ float sw1[CIN * DD], sw2[DD * DD], sb1[DD], sb2[DD];
    __shared__ float bufx[RPB][20], buft[RPB][36];
    __shared__ float sstat[2 * DD];
    int tid = threadIdx.x;
    for (int t = tid; t < CIN * DD; t += 256) sw1[t] = w1[t];
    for (int t = tid; t < DD * DD; t += 256) sw2[t] = w2[t];
    if (tid < DD) { sb1[tid] = b1[tid]; sb2[tid] = b2[tid]; }
    if (tid < 2 * DD) sstat[tid] = 0.f;

    int r = tid >> 5, ch = tid & 31;
    int g = blockIdx.x * RPB + r;
    if (ch < CIN) bufx[r][ch] = x[(size_t)g * CIN + ch];
    __syncthreads();

    float acc = sb1[ch];
#pragma unroll
    for (int k4 = 0; k4 < CIN; k4 += 4) {
        float4 v = *(const float4*)&bufx[r][k4];
        acc = fmaf(v.x, sw1[(k4 + 0) * DD + ch], acc);
        acc = fmaf(v.y, sw1[(k4 + 1) * DD + ch], acc);
        acc = fmaf(v.z, sw1[(k4 + 2) * DD + ch], acc);
        acc = fmaf(v.w, sw1[(k4 + 3) * DD + ch], acc);
    }
    acc = elu_f(acc);
    buft[r][ch] = acc;
    __syncthreads();

    float o = sb2[ch];
#pragma unroll
    for (int k4 = 0; k4 < DD; k4 += 4) {
        float4 v = *(const float4*)&buft[r][k4];
        o = fmaf(v.x, sw2[(k4 + 0) * DD + ch], o);
        o = fmaf(v.y, sw2[(k4 + 1) * DD + ch], o);
        o = fmaf(v.z, sw2[(k4 + 2) * DD + ch], o);
        o = fmaf(v.w, sw2[(k4 + 3) * DD + ch], o);
    }
    o = elu_f(o);
    h[(size_t)g * DD + ch] = o;

    float s = o + __shfl_xor(o, 32);
    float q = o * o;
    q += __shfl_xor(q, 32);
    if ((tid & 32) == 0) { atomicAdd(&sstat[ch], s); atomicAdd(&sstat[DD + ch], q); }
    __syncthreads();
    if (tid < 2 * DD) atomicAdd(&ST(tid), sstat[tid]);
}

// ---------- K2: BN1 apply + h_l/s_l projections (32 thr/row) ----------
__global__ __launch_bounds__(256) void k_proj(const float* __restrict__ h,
    const float* __restrict__ stats,
    const float* __restrict__ g1, const float* __restrict__ b1g,
    const float* __restrict__ hw, const float* __restrict__ hb,
    const float* __restrict__ sw,
    float* __restrict__ xin, float* __restrict__ hl, float4* __restrict__ sl4)
{
    __shared__ float shw[DD * DD], ssw[DD * 3], sa[DD], sbp[DD], shb[DD];
    __shared__ float rrow[RPB][36];
    int tid = threadIdx.x;
    for (int t = tid; t < DD * DD; t += 256) shw[t] = hw[t];
    if (tid < DD * 3) ssw[tid] = sw[tid];
    if (tid < DD) {
        float mean = ST(tid) * (1.f / NPTS);
        float var = ST(32 + tid) * (1.f / NPTS) - mean * mean;
        float a = g1[tid] * rsqrtf(var + 1e-5f);
        sa[tid] = a;
        sbp[tid] = b1g[tid] - a * mean;
        shb[tid] = hb[tid];
    }
    __syncthreads();

    int r = tid >> 5, ch = tid & 31;
    int g = blockIdx.x * RPB + r;

    float v = fmaf(sa[ch], h[(size_t)g * DD + ch], sbp[ch]);
    xin[(size_t)g * DD + ch] = v;
    rrow[r][ch] = v;

    float p0 = v * ssw[ch * 3 + 0];
    float p1 = v * ssw[ch * 3 + 1];
    float p2 = v * ssw[ch * 3 + 2];
    p0 = grp_sum32(p0); p1 = grp_sum32(p1); p2 = grp_sum32(p2);
    if (ch == 0) sl4[g] = make_float4(p0, p1, p2, 0.5f * (p0 * p0 + p1 * p1 + p2 * p2));
    __syncthreads();

    float o = shb[ch];
#pragma unroll
    for (int k4 = 0; k4 < DD; k4 += 4) {
        float4 vv = *(const float4*)&rrow[r][k4];
        o = fmaf(vv.x, shw[(k4 + 0) * DD + ch], o);
        o = fmaf(vv.y, shw[(k4 + 1) * DD + ch], o);
        o = fmaf(vv.z, shw[(k4 + 2) * DD + ch], o);
        o = fmaf(vv.w, shw[(k4 + 3) * DD + ch], o);
    }
    hl[(size_t)g * DD + ch] = o;
}

// ---------- K3: kNN — 2 queries/wave, e-form, collect-then-select ----------
__device__ __forceinline__ void select_emit(const float2* bufq, int C, int qidx,
    float qw, int lane, int* __restrict__ idxo, float* __restrict__ esq,
    float* __restrict__ sumd, float* __restrict__ indeg)
{
    float e0 = INFINITY, e1 = INFINITY;
    int j0 = -1, j1 = -1;
    if (lane < C) { float2 t = bufq[lane]; e0 = t.x; j0 = __float_as_int(t.y); }
    if (lane + 64 < C) { float2 t = bufq[lane + 64]; e1 = t.x; j1 = __float_as_int(t.y); }
    if (j0 == qidx) e0 = INFINITY;   // drop self
    if (j1 == qidx) e1 = INFINITY;
    unsigned u0 = fkey(e0), u1 = fkey(e1);
    unsigned thr = bisect_kth(u0, u1, KNN);
    unsigned long long ltm = (1ull << lane) - 1;
    unsigned long long mlt0 = __ballot(u0 < thr), mlt1 = __ballot(u1 < thr);
    unsigned long long meq0 = __ballot(u0 == thr), meq1 = __ballot(u1 == thr);
    int nlt = __popcll(mlt0) + __popcll(mlt1);
    int need = KNN - nlt;
    int rb = qidx * KNN;

    int pos = -1;
    if (u0 < thr) pos = __popcll(mlt0 & ltm);
    else if (u0 == thr) { int rk = __popcll(meq0 & ltm); if (rk < need) pos = nlt + rk; }
    if (pos >= 0) {
        float d2 = fmaxf(2.f * (e0 + qw), 0.f);
        idxo[rb + pos] = j0; esq[rb + pos] = d2;
        float dist = sqrtf(d2 + 1e-6f);
        atomicAdd(&sumd[j0], dist); atomicAdd(&indeg[j0], 1.f);
    }
    pos = -1;
    if (u1 < thr) pos = __popcll(mlt0) + __popcll(mlt1 & ltm);
    else if (u1 == thr) {
        int rk = __popcll(meq0) + __popcll(meq1 & ltm);
        if (rk < need) pos = nlt + rk;
    }
    if (pos >= 0) {
        float d2 = fmaxf(2.f * (e1 + qw), 0.f);
        idxo[rb + pos] = j1; esq[rb + pos] = d2;
        float dist = sqrtf(d2 + 1e-6f);
        atomicAdd(&sumd[j1], dist); atomicAdd(&indeg[j1], 1.f);
    }
}

__global__ __launch_bounds__(256) void k_knn(const float4* __restrict__ sl4,
    int* __restrict__ idxo, float* __restrict__ esq,
    float* __restrict__ sumd, float* __restrict__ indeg)
{
    __shared__ float2 buf[8][CAP];
    int tid = threadIdx.x, lane = tid & 63, wid = tid >> 6;
    int qai = blockIdx.x * 8 + wid * 2;
    int qbi = qai + 1;
    float4 qa = sl4[qai], qb = sl4[qbi];

    float m0a = INFINITY, m1a = INFINITY, m0b = INFINITY, m1b = INFINITY;
    for (int base = 0; base < NPTS; base += 64) {
        float4 p = sl4[base + lane];
        float ea = fmaf(-qa.x, p.x, fmaf(-qa.y, p.y, fmaf(-qa.z, p.z, p.w)));
        float eb = fmaf(-qb.x, p.x, fmaf(-qb.y, p.y, fmaf(-qb.z, p.z, p.w)));
        float lo = fminf(ea, m0a), hi = fmaxf(ea, m0a);
        m0a = lo; m1a = fminf(m1a, hi);
        lo = fminf(eb, m0b); hi = fmaxf(eb, m0b);
        m0b = lo; m1b = fminf(m1b, hi);
    }
    float thrfa = kinv(bisect_kth(fkey(m0a), fkey(m1a), KNN + 1));
    float thrfb = kinv(bisect_kth(fkey(m0b), fkey(m1b), KNN + 1));

    unsigned long long ltm = (1ull << lane) - 1;
    int ca = 0, cbn = 0;
    float2* bufa = buf[wid * 2];
    float2* bufb = buf[wid * 2 + 1];
    for (int base = 0; base < NPTS; base += 64) {
        float4 p = sl4[base + lane];
        int jj = base + lane;
        float ea = fmaf(-qa.x, p.x, fmaf(-qa.y, p.y, fmaf(-qa.z, p.z, p.w)));
        float eb = fmaf(-qb.x, p.x, fmaf(-qb.y, p.y, fmaf(-qb.z, p.z, p.w)));
        unsigned long long ma = __ballot(ea <= thrfa);
        unsigned long long mb = __ballot(eb <= thrfb);
        if (ma) {
            if (ea <= thrfa) {
                int pos = ca + __popcll(ma & ltm);
                if (pos < CAP) bufa[pos] = make_float2(ea, __int_as_float(jj));
            }
            ca += __popcll(ma);
        }
        if (mb) {
            if (eb <= thrfb) {
                int pos = cbn + __popcll(mb & ltm);
                if (pos < CAP) bufb[pos] = make_float2(eb, __int_as_float(jj));
            }
            cbn += __popcll(mb);
        }
    }
    __syncthreads();

    select_emit(bufa, ca < CAP ? ca : CAP, qai, qa.w, lane, idxo, esq, sumd, indeg);
    select_emit(bufb, cbn < CAP ? cbn : CAP, qbi, qb.w, lane, idxo, esq, sumd, indeg);
}

// ---------- K4: gather + lin + post-MLP + BN2 stats + losses (32 thr/row) ----------
__global__ __launch_bounds__(256) void k_agg(
    const int* __restrict__ idx, const float* __restrict__ esq,
    const float* __restrict__ hl, const float* __restrict__ xin,
    const float4* __restrict__ sl4,
    const float* __restrict__ sumd, const float* __restrict__ indeg,
    const float* __restrict__ lw, const float* __restrict__ lb,
    const float* __restrict__ pw1, const float* __restrict__ pb1,
    const float* __restrict__ pw2, const float* __restrict__ pb2,
    float* __restrict__ o, float* __restrict__ stats)
{
    __shared__ float slw[96 * DD], spw1[67 * DD], spw2[DD * DD];
    __shared__ float slb[DD], spb1[DD], spb2[DD];
    __shared__ float rbuf[RPB][100];   // [0,32) mean [32,64) max [64,96) xin [96,99) sl
    __shared__ float rb2[RPB][68];     // [0,32) xg  [32,64) o1
    __shared__ float sstat[2 * DD];
    __shared__ float sl1, sl2;
    int tid = threadIdx.x;
    for (int t = tid; t < 96 * DD; t += 256) slw[t] = lw[t];
    for (int t = tid; t < 67 * DD; t += 256) spw1[t] = pw1[t];
    for (int t = tid; t < DD * DD; t += 256) spw2[t] = pw2[t];
    if (tid < DD) { slb[tid] = lb[tid]; spb1[tid] = pb1[tid]; spb2[tid] = pb2[tid]; }
    if (tid < 2 * DD) sstat[tid] = 0.f;
    if (tid == 254) sl1 = 0.f;
    if (tid == 255) sl2 = 0.f;

    int r = tid >> 5, ch = tid & 31;
    int g = blockIdx.x * RPB + r;
    int rb = g * KNN;

    // ---- gather: this thread's channel over all 40 neighbors ----
    float sv = 0.f, mv = -INFINITY;
#pragma unroll 8
    for (int k = 0; k < KNN; ++k) {
        int j = idx[rb + k];
        float w = esq[rb + k];
        float m = hl[(size_t)j * DD + ch] * w;
        sv += m;
        mv = fmaxf(mv, m);
    }
    rbuf[r][ch] = sv * (1.f / KNN);
    rbuf[r][32 + ch] = mv;
    rbuf[r][64 + ch] = xin[(size_t)g * DD + ch];
    if (ch == 0) { float4 s = sl4[g]; rbuf[r][96] = s.x; rbuf[r][97] = s.y; rbuf[r][98] = s.z; }
    __syncthreads();

    // ---- per-edge losses, once per row (lane ch: edge ch, +edge 32+ch if ch<8) ----
    float l2 = 0.f;
    {
        int j = idx[rb + ch];
        float w = esq[rb + ch];
        float dist = sqrtf(w + 1e-6f);
        float sd = sumd[j];
        float r1 = 1.f / (sd + 1e-4f);
        float dg = sd * r1 + 1e-4f;            // degs2[j] closed form
        float df = dist * r1 - dist / dg;
        l2 = df * df;
        if (ch < KNN - 32) {
            j = idx[rb + 32 + ch];
            w = esq[rb + 32 + ch];
            dist = sqrtf(w + 1e-6f);
            sd = sumd[j];
            r1 = 1.f / (sd + 1e-4f);
            dg = sd * r1 + 1e-4f;
            df = dist * r1 - dist / dg;
            l2 += df * df;
        }
    }
    l2 = grp_sum32(l2);
    if (ch == 0) {
        float id = indeg[g], sdg = sumd[g];
        float av = id > 0.f ? sdg / fmaxf(id, 1.f) : 0.f;
        float dd = av - 0.5f;
        atomicAdd(&sl2, l2);
        atomicAdd(&sl1, dd * dd);
    }

    // ---- GEMM1: xg = [mean|max|xin] @ lin_w + lin_b ----
    float acc = slb[ch];
#pragma unroll
    for (int k4 = 0; k4 < 96; k4 += 4) {
        float4 v = *(const float4*)&rbuf[r][k4];
        acc = fmaf(v.x, slw[(k4 + 0) * DD + ch], acc);
        acc = fmaf(v.y, slw[(k4 + 1) * DD + ch], acc);
        acc = fmaf(v.z, slw[(k4 + 2) * DD + ch], acc);
        acc = fmaf(v.w, slw[(k4 + 3) * DD + ch], acc);
    }
    rb2[r][ch] = acc;
    __syncthreads();

    // ---- GEMM2: o1 = elu([xg|s_l|xin] @ post_w1 + post_b1) ----
    acc = spb1[ch];
#pragma unroll
    for (int k4 = 0; k4 < DD; k4 += 4) {
        float4 v = *(const float4*)&rb2[r][k4];
        acc = fmaf(v.x, spw1[(k4 + 0) * DD + ch], acc);
        acc = fmaf(v.y, spw1[(k4 + 1) * DD + ch], acc);
        acc = fmaf(v.z, spw1[(k4 + 2) * DD + ch], acc);
        acc = fmaf(v.w, spw1[(k4 + 3) * DD + ch], acc);
    }
#pragma unroll
    for (int s2 = 0; s2 < 3; ++s2)
        acc = fmaf(rbuf[r][96 + s2], spw1[(32 + s2) * DD + ch], acc);
#pragma unroll
    for (int k4 = 0; k4 < DD; k4 += 4) {
        float4 v = *(const float4*)&rbuf[r][64 + k4];
        acc = fmaf(v.x, spw1[(35 + k4 + 0) * DD + ch], acc);
        acc = fmaf(v.y, spw1[(35 + k4 + 1) * DD + ch], acc);
        acc = fmaf(v.z, spw1[(35 + k4 + 2) * DD + ch], acc);
        acc = fmaf(v.w, spw1[(35 + k4 + 3) * DD + ch], acc);
    }
    acc = elu_f(acc);
    rb2[r][32 + ch] = acc;
    __syncthreads();

    // ---- GEMM3: o2 = elu(o1 @ post_w2 + post_b2) ----
    acc = spb2[ch];
#pragma unroll
    for (int k4 = 0; k4 < DD; k4 += 4) {
        float4 v = *(const float4*)&rb2[r][32 + k4];
        acc = fmaf(v.x, spw2[(k4 + 0) * DD + ch], acc);
        acc = fmaf(v.y, spw2[(k4 + 1) * DD + ch], acc);
        acc = fmaf(v.z, spw2[(k4 + 2) * DD + ch], acc);
        acc = fmaf(v.w, spw2[(k4 + 3) * DD + ch], acc);
    }
    acc = elu_f(acc);
    o[(size_t)g * DD + ch] = acc;

    // ---- BN2 stats ----
    float s = acc + __shfl_xor(acc, 32);
    float q = acc * acc;
    q += __shfl_xor(q, 32);
    if ((tid & 32) == 0) { atomicAdd(&sstat[ch], s); atomicAdd(&sstat[DD + ch], q); }
    __syncthreads();
    if (tid < 2 * DD) atomicAdd(&ST(64 + tid), sstat[tid]);
    if (tid == 0) { atomicAdd(&ST(128), sl1); atomicAdd(&ST(129), sl2); }
}

// ---------- K5: BN2 apply (float4) + loss writes ----------
__global__ __launch_bounds__(256) void k_out(const float* __restrict__ o,
    const float* __restrict__ stats, const float* __restrict__ g,
    const float* __restrict__ b, float* __restrict__ dout)
{
    __shared__ float sa[DD], sb[DD];
    int tid = threadIdx.x;
    if (tid < DD) {
        float mean = ST(64 + tid) * (1.f / NPTS);
        float var = ST(96 + tid) * (1.f / NPTS) - mean * mean;
        float a = g[tid] * rsqrtf(var + 1e-5f);
        sa[tid] = a;
        sb[tid] = b[tid] - a * mean;
    }
    __syncthreads();

    int t = blockIdx.x * 256 + tid;                 // float4 index over 65536
    float4 v = ((const float4*)o)[t];
    int cbase = (t * 4) & (DD - 1);
    float4 rr;
    rr.x = fmaf(sa[cbase + 0], v.x, sb[cbase + 0]);
    rr.y = fmaf(sa[cbase + 1], v.y, sb[cbase + 1]);
    rr.z = fmaf(sa[cbase + 2], v.z, sb[cbase + 2]);
    rr.w = fmaf(sa[cbase + 3], v.w, sb[cbase + 3]);
    ((float4*)dout)[t] = rr;

    if (blockIdx.x == 0) {
        if (tid == DD)     dout[NPTS * DD]     = 0.01f * ST(128) * (1.f / NPTS);
        if (tid == DD + 1) dout[NPTS * DD + 1] = 0.1f  * ST(129) * (1.f / ((float)NPTS * KNN));
    }
}

extern "C" void kernel_launch(void* const* d_in, const int* in_sizes, int n_in,
                              void* d_out, int out_size, void* d_ws, size_t ws_size,
                              hipStream_t stream)
{
    (void)in_sizes; (void)n_in; (void)out_size; (void)ws_size;
    const float* x      = (const float*)d_in[0];
    const float* pre_w1 = (const float*)d_in[5];
    const float* pre_b1 = (const float*)d_in[6];
    const float* pre_w2 = (const float*)d_in[7];
    const float* pre_b2 = (const float*)d_in[8];
    const float* bn1_g  = (const float*)d_in[9];
    const float* bn1_b  = (const float*)d_in[10];
    const float* lin_s_w = (const float*)d_in[11];
    const float* lin_h_w = (const float*)d_in[12];
    const float* lin_h_b = (const float*)d_in[13];
    const float* lin_w   = (const float*)d_in[14];
    const float* lin_b   = (const float*)d_in[15];
    const float* post_w1 = (const float*)d_in[16];
    const float* post_b1 = (const float*)d_in[17];
    const float* post_w2 = (const float*)d_in[18];
    const float* post_b2 = (const float*)d_in[19];
    const float* bn2_g   = (const float*)d_in[20];
    const float* bn2_b   = (const float*)d_in[21];

    float* W = (float*)d_ws;
    float* h     = W + OFF_H;
    float* xin   = W + OFF_XIN;
    float* hl    = W + OFF_HL;
    float4* sl4  = (float4*)(W + OFF_SL);
    float* esq   = W + OFF_ESQ;
    float* o     = W + OFF_O;
    int*   idx   = (int*)(W + OFF_IDX);
    float* sumd  = W + OFF_SUMD;
    float* indeg = W + OFF_INDEG;
    float* stats = W + OFF_STATS;
    float* dout  = (float*)d_out;

    hipMemsetAsync(W + OFF_SUMD, 0, ZERO_FLOATS * sizeof(float), stream);

    k_pre<<<NPTS / RPB, 256, 0, stream>>>(x, pre_w1, pre_b1, pre_w2, pre_b2, h, stats);
    k_proj<<<NPTS / RPB, 256, 0, stream>>>(h, stats, bn1_g, bn1_b,
                                           lin_h_w, lin_h_b, lin_s_w, xin, hl, sl4);
    k_knn<<<NPTS / 8, 256, 0, stream>>>(sl4, idx, esq, sumd, indeg);
    k_agg<<<NPTS / RPB, 256, 0, stream>>>(idx, esq, hl, xin, sl4, sumd, indeg,
                                          lin_w, lin_b, post_w1, post_b1, post_w2, post_b2,
                                          o, stats);
    k_out<<<NPTS * DD / 1024, 256, 0, stream>>>(o, stats, bn2_g, bn2_b, dout);
}

// Round 7
// 122.920 us; speedup vs baseline: 37.1328x; 1.0731x over previous
//
#include <hip/hip_runtime.h>
#include <math.h>

#define NPTS 8192
#define KNN 40
#define DD 32
#define CIN 16
#define RPB 8        // rows per block (32 threads per row)
#define CAP 96       // kNN candidate buffer per query

// ---- ws layout (float offsets) ----
#define OFF_H      0u         // 8192*32
#define OFF_XIN    262144u    // 8192*32
#define OFF_HL     524288u    // 8192*32
#define OFF_SL     786432u    // 8192*4 (float4: s0,s1,s2, 0.5*|s|^2)
#define OFF_ESQ    819200u    // 8192*40
#define OFF_O      1146880u   // 8192*32
#define OFF_IDX    1409024u   // 8192*40 (int)
#define OFF_SUMD   1736704u   // 8192
#define OFF_INDEG  1744896u   // 8192
#define OFF_STATS  1753088u   // 130 slots x 32-float stride (1 line/slot)
#define ZERO_FLOATS (8192u + 8192u + 130u * 32u)

// slot map: 0..31 bn1 sum, 32..63 bn1 sq, 64..95 bn2 sum, 96..127 bn2 sq,
//           128 loss1, 129 loss2
#define ST(i) stats[(i) * 32]

__device__ __forceinline__ float elu_f(float x) { return x > 0.f ? x : (expf(x) - 1.f); }

__device__ __forceinline__ float grp_sum32(float v) {
#pragma unroll
    for (int m = 1; m < 32; m <<= 1) v += __shfl_xor(v, m);
    return v;
}

// order-preserving float->uint key
__device__ __forceinline__ unsigned fkey(float x) {
    unsigned b = __float_as_uint(x);
    return b ^ ((unsigned)((int)b >> 31) | 0x80000000u);
}
__device__ __forceinline__ float kinv(unsigned k) {
    unsigned b = (k & 0x80000000u) ? (k ^ 0x80000000u) : ~k;
    return __uint_as_float(b);
}

// kth-smallest (1-based) of the 128 values {u0,u1} x 64 lanes, exact
__device__ __forceinline__ unsigned bisect_kth(unsigned u0, unsigned u1, int kth) {
    unsigned lo = 0u, hi = 0xFFFFFFFFu;
    while (lo < hi) {
        unsigned mid = lo + ((hi - lo) >> 1);
        int cnt = __popcll(__ballot(u0 <= mid)) + __popcll(__ballot(u1 <= mid));
        if (cnt >= kth) hi = mid; else lo = mid + 1;
    }
    return hi;
}

// ---------- K1: pre-MLP + BN1 stats (32 thr/row, 1 ch/thr) ----------
__global__ __launch_bounds__(256) void k_pre(const float* __restrict__ x,
    const float* __restrict__ w1, const float* __restrict__ b1,
    const float* __restrict__ w2, const float* __restrict__ b2,
    float* __restrict__ h, float* __restrict__ stats)
{
    __shared__ float sw1[CIN * DD], sw2[DD * DD], sb1[DD], sb2[DD];
    __shared__ float bufx[RPB][20], buft[RPB][36];
    __shared__ float sstat[2 * DD];
    int tid = threadIdx.x;
    for (int t = tid; t < CIN * DD; t += 256) sw1[t] = w1[t];
    for (int t = tid; t < DD * DD; t += 256) sw2[t] = w2[t];
    if (tid < DD) { sb1[tid] = b1[tid]; sb2[tid] = b2[tid]; }
    if (tid < 2 * DD) sstat[tid] = 0.f;

    int r = tid >> 5, ch = tid & 31;
    int g = blockIdx.x * RPB + r;
    if (ch < CIN) bufx[r][ch] = x[(size_t)g * CIN + ch];
    __syncthreads();

    float acc = sb1[ch];
#pragma unroll
    for (int k4 = 0; k4 < CIN; k4 += 4) {
        float4 v = *(const float4*)&bufx[r][k4];
        acc = fmaf(v.x, sw1[(k4 + 0) * DD + ch], acc);
        acc = fmaf(v.y, sw1[(k4 + 1) * DD + ch], acc);
        acc = fmaf(v.z, sw1[(k4 + 2) * DD + ch], acc);
        acc = fmaf(v.w, sw1[(k4 + 3) * DD + ch], acc);
    }
    acc = elu_f(acc);
    buft[r][ch] = acc;
    __syncthreads();

    float o = sb2[ch];
#pragma unroll
    for (int k4 = 0; k4 < DD; k4 += 4) {
        float4 v = *(const float4*)&buft[r][k4];
        o = fmaf(v.x, sw2[(k4 + 0) * DD + ch], o);
        o = fmaf(v.y, sw2[(k4 + 1) * DD + ch], o);
        o = fmaf(v.z, sw2[(k4 + 2) * DD + ch], o);
        o = fmaf(v.w, sw2[(k4 + 3) * DD + ch], o);
    }
    o = elu_f(o);
    h[(size_t)g * DD + ch] = o;

    float s = o + __shfl_xor(o, 32);
    float q = o * o;
    q += __shfl_xor(q, 32);
    if ((tid & 32) == 0) { atomicAdd(&sstat[ch], s); atomicAdd(&sstat[DD + ch], q); }
    __syncthreads();
    if (tid < 2 * DD) atomicAdd(&ST(tid), sstat[tid]);
}

// ---------- K2: BN1 apply + h_l/s_l projections (32 thr/row) ----------
__global__ __launch_bounds__(256) void k_proj(const float* __restrict__ h,
    const float* __restrict__ stats,
    const float* __restrict__ g1, const float* __restrict__ b1g,
    const float* __restrict__ hw, const float* __restrict__ hb,
    const float* __restrict__ sw,
    float* __restrict__ xin, float* __restrict__ hl, float4* __restrict__ sl4)
{
    __shared__ float shw[DD * DD], ssw[DD * 3], sa[DD], sbp[DD], shb[DD];
    __shared__ float rrow[RPB][36];
    int tid = threadIdx.x;
    for (int t = tid; t < DD * DD; t += 256) shw[t] = hw[t];
    if (tid < DD * 3) ssw[tid] = sw[tid];
    if (tid < DD) {
        float mean = ST(tid) * (1.f / NPTS);
        float var = ST(32 + tid) * (1.f / NPTS) - mean * mean;
        float a = g1[tid] * rsqrtf(var + 1e-5f);
        sa[tid] = a;
        sbp[tid] = b1g[tid] - a * mean;
        shb[tid] = hb[tid];
    }
    __syncthreads();

    int r = tid >> 5, ch = tid & 31;
    int g = blockIdx.x * RPB + r;

    float v = fmaf(sa[ch], h[(size_t)g * DD + ch], sbp[ch]);
    xin[(size_t)g * DD + ch] = v;
    rrow[r][ch] = v;

    float p0 = v * ssw[ch * 3 + 0];
    float p1 = v * ssw[ch * 3 + 1];
    float p2 = v * ssw[ch * 3 + 2];
    p0 = grp_sum32(p0); p1 = grp_sum32(p1); p2 = grp_sum32(p2);
    if (ch == 0) sl4[g] = make_float4(p0, p1, p2, 0.5f * (p0 * p0 + p1 * p1 + p2 * p2));
    __syncthreads();

    float o = shb[ch];
#pragma unroll
    for (int k4 = 0; k4 < DD; k4 += 4) {
        float4 vv = *(const float4*)&rrow[r][k4];
        o = fmaf(vv.x, shw[(k4 + 0) * DD + ch], o);
        o = fmaf(vv.y, shw[(k4 + 1) * DD + ch], o);
        o = fmaf(vv.z, shw[(k4 + 2) * DD + ch], o);
        o = fmaf(vv.w, shw[(k4 + 3) * DD + ch], o);
    }
    hl[(size_t)g * DD + ch] = o;
}

// ---------- K3: kNN — 2 q/wave, e-form, 4-deep prefetch, collect-then-select ---
__device__ __forceinline__ void select_emit(const float2* bufq, int C, int qidx,
    float qw, int lane, int* __restrict__ idxo, float* __restrict__ esq,
    float* __restrict__ sumd, float* __restrict__ indeg)
{
    float e0 = INFINITY, e1 = INFINITY;
    int j0 = -1, j1 = -1;
    if (lane < C) { float2 t = bufq[lane]; e0 = t.x; j0 = __float_as_int(t.y); }
    if (lane + 64 < C) { float2 t = bufq[lane + 64]; e1 = t.x; j1 = __float_as_int(t.y); }
    if (j0 == qidx) e0 = INFINITY;   // drop self
    if (j1 == qidx) e1 = INFINITY;
    unsigned u0 = fkey(e0), u1 = fkey(e1);
    unsigned thr = bisect_kth(u0, u1, KNN);
    unsigned long long ltm = (1ull << lane) - 1;
    unsigned long long mlt0 = __ballot(u0 < thr), mlt1 = __ballot(u1 < thr);
    unsigned long long meq0 = __ballot(u0 == thr), meq1 = __ballot(u1 == thr);
    int nlt = __popcll(mlt0) + __popcll(mlt1);
    int need = KNN - nlt;
    int rb = qidx * KNN;

    int pos = -1;
    if (u0 < thr) pos = __popcll(mlt0 & ltm);
    else if (u0 == thr) { int rk = __popcll(meq0 & ltm); if (rk < need) pos = nlt + rk; }
    if (pos >= 0) {
        float d2 = fmaxf(2.f * (e0 + qw), 0.f);
        idxo[rb + pos] = j0; esq[rb + pos] = d2;
        float dist = sqrtf(d2 + 1e-6f);
        atomicAdd(&sumd[j0], dist); atomicAdd(&indeg[j0], 1.f);
    }
    pos = -1;
    if (u1 < thr) pos = __popcll(mlt0) + __popcll(mlt1 & ltm);
    else if (u1 == thr) {
        int rk = __popcll(meq0) + __popcll(meq1 & ltm);
        if (rk < need) pos = nlt + rk;
    }
    if (pos >= 0) {
        float d2 = fmaxf(2.f * (e1 + qw), 0.f);
        idxo[rb + pos] = j1; esq[rb + pos] = d2;
        float dist = sqrtf(d2 + 1e-6f);
        atomicAdd(&sumd[j1], dist); atomicAdd(&indeg[j1], 1.f);
    }
}

__global__ __launch_bounds__(256) void k_knn(const float4* __restrict__ sl4,
    int* __restrict__ idxo, float* __restrict__ esq,
    float* __restrict__ sumd, float* __restrict__ indeg)
{
    __shared__ float2 buf[8][CAP];
    int tid = threadIdx.x, lane = tid & 63, wid = tid >> 6;
    int qai = blockIdx.x * 8 + wid * 2;
    int qbi = qai + 1;
    float4 qa = sl4[qai], qb = sl4[qbi];

    // ---- pass 1: per-lane top-2 of e, 4-deep prefetched ----
    float m0a = INFINITY, m1a = INFINITY, m0b = INFINITY, m1b = INFINITY;
    float4 c0 = sl4[lane], c1 = sl4[64 + lane], c2 = sl4[128 + lane], c3 = sl4[192 + lane];

#define EDIST(p, qq) fmaf(-(qq).x, (p).x, fmaf(-(qq).y, (p).y, fmaf(-(qq).z, (p).z, (p).w)))
#define TOP2(p) { \
        float ea = EDIST(p, qa), eb = EDIST(p, qb); \
        float lo = fminf(ea, m0a), hi = fmaxf(ea, m0a); \
        m0a = lo; m1a = fminf(m1a, hi); \
        lo = fminf(eb, m0b); hi = fmaxf(eb, m0b); \
        m0b = lo; m1b = fminf(m1b, hi); }

    for (int base = 0; base < NPTS; base += 256) {
        int nb = (base + 256) & (NPTS - 1);
        float4 n0 = sl4[nb + lane];
        float4 n1 = sl4[nb + 64 + lane];
        float4 n2 = sl4[nb + 128 + lane];
        float4 n3 = sl4[nb + 192 + lane];
        TOP2(c0) TOP2(c1) TOP2(c2) TOP2(c3)
        c0 = n0; c1 = n1; c2 = n2; c3 = n3;
    }
    float thrfa = kinv(bisect_kth(fkey(m0a), fkey(m1a), KNN + 1));
    float thrfb = kinv(bisect_kth(fkey(m0b), fkey(m1b), KNN + 1));

    // ---- pass 2: collect candidates <= thr, 4-deep prefetched ----
    unsigned long long ltm = (1ull << lane) - 1;
    int ca = 0, cbn = 0;
    float2* bufa = buf[wid * 2];
    float2* bufb = buf[wid * 2 + 1];
    c0 = sl4[lane]; c1 = sl4[64 + lane]; c2 = sl4[128 + lane]; c3 = sl4[192 + lane];

#define COLLECT(p, off) { \
        int jj = base + (off) + lane; \
        float ea = EDIST(p, qa), eb = EDIST(p, qb); \
        unsigned long long ma = __ballot(ea <= thrfa); \
        unsigned long long mb = __ballot(eb <= thrfb); \
        if (ma) { \
            if (ea <= thrfa) { \
                int pos = ca + __popcll(ma & ltm); \
                if (pos < CAP) bufa[pos] = make_float2(ea, __int_as_float(jj)); \
            } \
            ca += __popcll(ma); \
        } \
        if (mb) { \
            if (eb <= thrfb) { \
                int pos = cbn + __popcll(mb & ltm); \
                if (pos < CAP) bufb[pos] = make_float2(eb, __int_as_float(jj)); \
            } \
            cbn += __popcll(mb); \
        } }

    for (int base = 0; base < NPTS; base += 256) {
        int nb = (base + 256) & (NPTS - 1);
        float4 n0 = sl4[nb + lane];
        float4 n1 = sl4[nb + 64 + lane];
        float4 n2 = sl4[nb + 128 + lane];
        float4 n3 = sl4[nb + 192 + lane];
        COLLECT(c0, 0) COLLECT(c1, 64) COLLECT(c2, 128) COLLECT(c3, 192)
        c0 = n0; c1 = n1; c2 = n2; c3 = n3;
    }
    __syncthreads();

    select_emit(bufa, ca < CAP ? ca : CAP, qai, qa.w, lane, idxo, esq, sumd, indeg);
    select_emit(bufb, cbn < CAP ? cbn : CAP, qbi, qb.w, lane, idxo, esq, sumd, indeg);
}

// ---------- K4: gather + lin + post-MLP + BN2 stats + losses (32 thr/row) ----------
__global__ __launch_bounds__(256) void k_agg(
    const int* __restrict__ idx, const float* __restrict__ esq,
    const float* __restrict__ hl, const float* __restrict__ xin,
    const float4* __restrict__ sl4,
    const float* __restrict__ sumd, const float* __restrict__ indeg,
    const float* __restrict__ lw, const float* __restrict__ lb,
    const float* __restrict__ pw1, const float* __restrict__ pb1,
    const float* __restrict__ pw2, const float* __restrict__ pb2,
    float* __restrict__ o, float* __restrict__ stats)
{
    __shared__ float slw[96 * DD], spw1[67 * DD], spw2[DD * DD];
    __shared__ float slb[DD], spb1[DD], spb2[DD];
    __shared__ float rbuf[RPB][100];   // [0,32) mean [32,64) max [64,96) xin [96,99) sl
    __shared__ float rb2[RPB][68];     // [0,32) xg  [32,64) o1
    __shared__ float sstat[2 * DD];
    __shared__ float sl1, sl2;
    int tid = threadIdx.x;
    for (int t = tid; t < 96 * DD; t += 256) slw[t] = lw[t];
    for (int t = tid; t < 67 * DD; t += 256) spw1[t] = pw1[t];
    for (int t = tid; t < DD * DD; t += 256) spw2[t] = pw2[t];
    if (tid < DD) { slb[tid] = lb[tid]; spb1[tid] = pb1[tid]; spb2[tid] = pb2[tid]; }
    if (tid < 2 * DD) sstat[tid] = 0.f;
    if (tid == 254) sl1 = 0.f;
    if (tid == 255) sl2 = 0.f;

    int r = tid >> 5, ch = tid & 31;
    int g = blockIdx.x * RPB + r;
    int rb = g * KNN;

    // ---- gather: this thread's channel over all 40 neighbors ----
    float sv = 0.f, mv = -INFINITY;
#pragma unroll 8
    for (int k = 0; k < KNN; ++k) {
        int j = idx[rb + k];
        float w = esq[rb + k];
        float m = hl[(size_t)j * DD + ch] * w;
        sv += m;
        mv = fmaxf(mv, m);
    }
    rbuf[r][ch] = sv * (1.f / KNN);
    rbuf[r][32 + ch] = mv;
    rbuf[r][64 + ch] = xin[(size_t)g * DD + ch];
    if (ch == 0) { float4 s = sl4[g]; rbuf[r][96] = s.x; rbuf[r][97] = s.y; rbuf[r][98] = s.z; }
    __syncthreads();

    // ---- per-edge losses, once per row ----
    float l2 = 0.f;
    {
        int j = idx[rb + ch];
        float w = esq[rb + ch];
        float dist = sqrtf(w + 1e-6f);
        float sd = sumd[j];
        float r1 = 1.f / (sd + 1e-4f);
        float dg = sd * r1 + 1e-4f;            // degs2[j] closed form
        float df = dist * r1 - dist / dg;
        l2 = df * df;
        if (ch < KNN - 32) {
            j = idx[rb + 32 + ch];
            w = esq[rb + 32 + ch];
            dist = sqrtf(w + 1e-6f);
            sd = sumd[j];
            r1 = 1.f / (sd + 1e-4f);
            dg = sd * r1 + 1e-4f;
            df = dist * r1 - dist / dg;
            l2 += df * df;
        }
    }
    l2 = grp_sum32(l2);
    if (ch == 0) {
        float id = indeg[g], sdg = sumd[g];
        float av = id > 0.f ? sdg / fmaxf(id, 1.f) : 0.f;
        float dd = av - 0.5f;
        atomicAdd(&sl2, l2);
        atomicAdd(&sl1, dd * dd);
    }

    // ---- GEMM1: xg = [mean|max|xin] @ lin_w + lin_b ----
    float acc = slb[ch];
#pragma unroll
    for (int k4 = 0; k4 < 96; k4 += 4) {
        float4 v = *(const float4*)&rbuf[r][k4];
        acc = fmaf(v.x, slw[(k4 + 0) * DD + ch], acc);
        acc = fmaf(v.y, slw[(k4 + 1) * DD + ch], acc);
        acc = fmaf(v.z, slw[(k4 + 2) * DD + ch], acc);
        acc = fmaf(v.w, slw[(k4 + 3) * DD + ch], acc);
    }
    rb2[r][ch] = acc;
    __syncthreads();

    // ---- GEMM2: o1 = elu([xg|s_l|xin] @ post_w1 + post_b1) ----
    acc = spb1[ch];
#pragma unroll
    for (int k4 = 0; k4 < DD; k4 += 4) {
        float4 v = *(const float4*)&rb2[r][k4];
        acc = fmaf(v.x, spw1[(k4 + 0) * DD + ch], acc);
        acc = fmaf(v.y, spw1[(k4 + 1) * DD + ch], acc);
        acc = fmaf(v.z, spw1[(k4 + 2) * DD + ch], acc);
        acc = fmaf(v.w, spw1[(k4 + 3) * DD + ch], acc);
    }
#pragma unroll
    for (int s2 = 0; s2 < 3; ++s2)
        acc = fmaf(rbuf[r][96 + s2], spw1[(32 + s2) * DD + ch], acc);
#pragma unroll
    for (int k4 = 0; k4 < DD; k4 += 4) {
        float4 v = *(const float4*)&rbuf[r][64 + k4];
        acc = fmaf(v.x, spw1[(35 + k4 + 0) * DD + ch], acc);
        acc = fmaf(v.y, spw1[(35 + k4 + 1) * DD + ch], acc);
        acc = fmaf(v.z, spw1[(35 + k4 + 2) * DD + ch], acc);
        acc = fmaf(v.w, spw1[(35 + k4 + 3) * DD + ch], acc);
    }
    acc = elu_f(acc);
    rb2[r][32 + ch] = acc;
    __syncthreads();

    // ---- GEMM3: o2 = elu(o1 @ post_w2 + post_b2) ----
    acc = spb2[ch];
#pragma unroll
    for (int k4 = 0; k4 < DD; k4 += 4) {
        float4 v = *(const float4*)&rb2[r][32 + k4];
        acc = fmaf(v.x, spw2[(k4 + 0) * DD + ch], acc);
        acc = fmaf(v.y, spw2[(k4 + 1) * DD + ch], acc);
        acc = fmaf(v.z, spw2[(k4 + 2) * DD + ch], acc);
        acc = fmaf(v.w, spw2[(k4 + 3) * DD + ch], acc);
    }
    acc = elu_f(acc);
    o[(size_t)g * DD + ch] = acc;

    // ---- BN2 stats ----
    float s = acc + __shfl_xor(acc, 32);
    float q = acc * acc;
    q += __shfl_xor(q, 32);
    if ((tid & 32) == 0) { atomicAdd(&sstat[ch], s); atomicAdd(&sstat[DD + ch], q); }
    __syncthreads();
    if (tid < 2 * DD) atomicAdd(&ST(64 + tid), sstat[tid]);
    if (tid == 0) { atomicAdd(&ST(128), sl1); atomicAdd(&ST(129), sl2); }
}

// ---------- K5: BN2 apply (float4) + loss writes ----------
__global__ __launch_bounds__(256) void k_out(const float* __restrict__ o,
    const float* __restrict__ stats, const float* __restrict__ g,
    const float* __restrict__ b, float* __restrict__ dout)
{
    __shared__ float sa[DD], sb[DD];
    int tid = threadIdx.x;
    if (tid < DD) {
        float mean = ST(64 + tid) * (1.f / NPTS);
        float var = ST(96 + tid) * (1.f / NPTS) - mean * mean;
        float a = g[tid] * rsqrtf(var + 1e-5f);
        sa[tid] = a;
        sb[tid] = b[tid] - a * mean;
    }
    __syncthreads();

    int t = blockIdx.x * 256 + tid;                 // float4 index over 65536
    float4 v = ((const float4*)o)[t];
    int cbase = (t * 4) & (DD - 1);
    float4 rr;
    rr.x = fmaf(sa[cbase + 0], v.x, sb[cbase + 0]);
    rr.y = fmaf(sa[cbase + 1], v.y, sb[cbase + 1]);
    rr.z = fmaf(sa[cbase + 2], v.z, sb[cbase + 2]);
    rr.w = fmaf(sa[cbase + 3], v.w, sb[cbase + 3]);
    ((float4*)dout)[t] = rr;

    if (blockIdx.x == 0) {
        if (tid == DD)     dout[NPTS * DD]     = 0.01f * ST(128) * (1.f / NPTS);
        if (tid == DD + 1) dout[NPTS * DD + 1] = 0.1f  * ST(129) * (1.f / ((float)NPTS * KNN));
    }
}

extern "C" void kernel_launch(void* const* d_in, const int* in_sizes, int n_in,
                              void* d_out, int out_size, void* d_ws, size_t ws_size,
                              hipStream_t stream)
{
    (void)in_sizes; (void)n_in; (void)out_size; (void)ws_size;
    const float* x      = (const float*)d_in[0];
    const float* pre_w1 = (const float*)d_in[5];
    const float* pre_b1 = (const float*)d_in[6];
    const float* pre_w2 = (const float*)d_in[7];
    const float* pre_b2 = (const float*)d_in[8];
    const float* bn1_g  = (const float*)d_in[9];
    const float* bn1_b  = (const float*)d_in[10];
    const float* lin_s_w = (const float*)d_in[11];
    const float* lin_h_w = (const float*)d_in[12];
    const float* lin_h_b = (const float*)d_in[13];
    const float* lin_w   = (const float*)d_in[14];
    const float* lin_b   = (const float*)d_in[15];
    const float* post_w1 = (const float*)d_in[16];
    const float* post_b1 = (const float*)d_in[17];
    const float* post_w2 = (const float*)d_in[18];
    const float* post_b2 = (const float*)d_in[19];
    const float* bn2_g   = (const float*)d_in[20];
    const float* bn2_b   = (const float*)d_in[21];

    float* W = (float*)d_ws;
    float* h     = W + OFF_H;
    float* xin   = W + OFF_XIN;
    float* hl    = W + OFF_HL;
    float4* sl4  = (float4*)(W + OFF_SL);
    float* esq   = W + OFF_ESQ;
    float* o     = W + OFF_O;
    int*   idx   = (int*)(W + OFF_IDX);
    float* sumd  = W + OFF_SUMD;
    float* indeg = W + OFF_INDEG;
    float* stats = W + OFF_STATS;
    float* dout  = (float*)d_out;

    hipMemsetAsync(W + OFF_SUMD, 0, ZERO_FLOATS * sizeof(float), stream);

    k_pre<<<NPTS / RPB, 256, 0, stream>>>(x, pre_w1, pre_b1, pre_w2, pre_b2, h, stats);
    k_proj<<<NPTS / RPB, 256, 0, stream>>>(h, stats, bn1_g, bn1_b,
                                           lin_h_w, lin_h_b, lin_s_w, xin, hl, sl4);
    k_knn<<<NPTS / 8, 256, 0, stream>>>(sl4, idx, esq, sumd, indeg);
    k_agg<<<NPTS / RPB, 256, 0, stream>>>(idx, esq, hl, xin, sl4, sumd, indeg,
                                          lin_w, lin_b, post_w1, post_b1, post_w2, post_b2,
                                          o, stats);
    k_out<<<NPTS * DD / 1024, 256, 0, stream>>>(o, stats, bn2_g, bn2_b, dout);
}